// Round 1
// baseline (645.744 us; speedup 1.0000x reference)
//
#include <hip/hip_runtime.h>
#include <hip/hip_bf16.h>

#define N_NODES 100000
#define N_EDGES 800000
#define EPS 1e-5f
#define NBANK 32
#define HB_BLOCKS 256
#define HB_PER 3125          // 256 * 3125 = 800000 exactly
#define CS_GPB 64            // cscatter blocks per coarse bucket
#define BUCKET_N 12500       // 8 * 12500 = 100000 exactly
#define MROW 68              // LDS mean row stride in dwords (64 + 4 pad)
#define ACC_S 132            // LDS fp32 accumulator row stride (128 + 4 pad)

typedef __attribute__((ext_vector_type(8))) short short8;
typedef __attribute__((ext_vector_type(4))) float floatx4;

__device__ __forceinline__ unsigned short f2b(float f) {
    unsigned int u = __float_as_uint(f);
    u = (u + 0x7fffu + ((u >> 16) & 1u)) >> 16;   // round-to-nearest-even
    return (unsigned short)u;
}
__device__ __forceinline__ float blo(unsigned int u) { return __uint_as_float(u << 16); }
__device__ __forceinline__ float bhi(unsigned int u) { return __uint_as_float(u & 0xffff0000u); }

// ---------------- elementwise convert fp32 -> bf16 (x input) ----------------
__global__ void cvt_f32_bf16(const float* __restrict__ x, unsigned short* __restrict__ o, int n4) {
    int i = blockIdx.x * blockDim.x + threadIdx.x;
    if (i >= n4) return;
    float4 v = ((const float4*)x)[i];
    ushort4 r;
    r.x = f2b(v.x); r.y = f2b(v.y); r.z = f2b(v.z); r.w = f2b(v.w);
    ((ushort4*)o)[i] = r;
}

// ---------------- pack [Wl;Wr] (K=256 x Hreal) into MFMA B-fragment order ----
__global__ void pack_w(const float* __restrict__ Wl, const float* __restrict__ Wr,
                       unsigned short* __restrict__ out, int Hreal, int NCT) {
    int tid = blockIdx.x * blockDim.x + threadIdx.x;
    int total = NCT * 8 * 64 * 8;
    if (tid >= total) return;
    int i = tid & 7;
    int lane = (tid >> 3) & 63;
    int q = tid >> 9;
    int c = q % NCT;
    int t = q / NCT;
    int k = t * 32 + (lane >> 4) * 8 + i;
    int n = c * 16 + (lane & 15);
    float v = 0.f;
    if (n < Hreal) v = (k < 128) ? Wl[k * Hreal + n] : Wr[(k - 128) * Hreal + n];
    out[tid] = f2b(v);
}

// ---------------- CSR build: two-level counting sort -------------------------
__global__ void __launch_bounds__(256) hist_k(const int* __restrict__ dst,
                                              unsigned int* __restrict__ cnt,
                                              unsigned int* __restrict__ bhist) {
    __shared__ unsigned int lh[8];
    if (threadIdx.x < 8) lh[threadIdx.x] = 0;
    __syncthreads();
    int start = blockIdx.x * HB_PER;
    for (int i = threadIdx.x; i < HB_PER; i += 256) {
        int d = dst[start + i];
        atomicAdd(&cnt[d], 1u);
        atomicAdd(&lh[(unsigned int)d / BUCKET_N], 1u);
    }
    __syncthreads();
    if (threadIdx.x < 8) bhist[threadIdx.x * HB_BLOCKS + blockIdx.x] = lh[threadIdx.x];
}

__global__ void bscan(unsigned int* __restrict__ A) {
    __shared__ unsigned int part[256];
    int t = threadIdx.x;
    unsigned int v[8];
    unsigned int s = 0;
#pragma unroll
    for (int i = 0; i < 8; i++) { v[i] = A[t * 8 + i]; s += v[i]; }
    part[t] = s; __syncthreads();
    for (int off = 1; off < 256; off <<= 1) {
        unsigned int add = (t >= off) ? part[t - off] : 0u;
        __syncthreads();
        part[t] += add;
        __syncthreads();
    }
    unsigned int base = part[t] - s;  // exclusive
#pragma unroll
    for (int i = 0; i < 8; i++) { unsigned int old = v[i]; A[t * 8 + i] = base; base += old; }
}

__global__ void __launch_bounds__(256) bscatter(const int* __restrict__ src,
                                                const int* __restrict__ dst,
                                                const unsigned int* __restrict__ boffs,
                                                unsigned int* __restrict__ ebuf) {
    __shared__ unsigned int cur[8];
    if (threadIdx.x < 8) cur[threadIdx.x] = boffs[threadIdx.x * HB_BLOCKS + blockIdx.x];
    __syncthreads();
    int start = blockIdx.x * HB_PER;
    for (int i = threadIdx.x; i < HB_PER; i += 256) {
        int d = dst[start + i];
        int s = src[start + i];
        unsigned int b = (unsigned int)d / BUCKET_N;
        unsigned int dl = (unsigned int)d - b * BUCKET_N;
        unsigned int pos = atomicAdd(&cur[b], 1u);
        ebuf[pos] = (unsigned int)s | (dl << 17);
    }
}

// R10: pack dst-local row (node & 15, 4 bits) into bits 17-20 of srclist so the
// fused agg kernels can process edges independent of which node they hit.
__global__ void __launch_bounds__(256) cscatter(const unsigned int* __restrict__ ebuf,
                                                const unsigned int* __restrict__ rowptr,
                                                unsigned int* __restrict__ cursor,
                                                int* __restrict__ srclist) {
    int g = blockIdx.x & 7;
    int gblk = blockIdx.x >> 3;
    unsigned int estart = rowptr[g * BUCKET_N];
    unsigned int eend = (g == 7) ? N_EDGES : rowptr[(g + 1) * BUCKET_N];
    unsigned int nume = eend - estart;
    unsigned int per = (nume + CS_GPB - 1) / CS_GPB;
    unsigned int s0 = estart + gblk * per;
    unsigned int s1 = s0 + per; if (s1 > eend) s1 = eend;
    unsigned int nodebase = g * BUCKET_N;
    for (unsigned int i = s0 + threadIdx.x; i < s1; i += 256) {
        unsigned int p = ebuf[i];
        unsigned int s = p & 0x1FFFFu;
        unsigned int node = nodebase + (p >> 17);
        unsigned int pos = atomicAdd(&cursor[node], 1u);
        srclist[pos] = (int)(s | ((node & 15u) << 17));
    }
}

__global__ void scan1(const unsigned int* __restrict__ cnt, unsigned int* __restrict__ rowptr,
                      unsigned int* __restrict__ bsum) {
    __shared__ unsigned int sh[256];
    int t = threadIdx.x;
    int i = blockIdx.x * 256 + t;
    unsigned int v = (i < N_NODES) ? cnt[i] : 0u;
    sh[t] = v; __syncthreads();
    for (int off = 1; off < 256; off <<= 1) {
        unsigned int add = (t >= off) ? sh[t - off] : 0u;
        __syncthreads();
        sh[t] += add;
        __syncthreads();
    }
    if (i < N_NODES) rowptr[i] = sh[t] - v;  // exclusive within block
    if (t == 255) bsum[blockIdx.x] = sh[255];
}

__global__ void scan2(const unsigned int* __restrict__ bsum, unsigned int* __restrict__ boff, int nb) {
    __shared__ unsigned int sh[512];
    int t = threadIdx.x;
    unsigned int v = (t < nb) ? bsum[t] : 0u;
    sh[t] = v; __syncthreads();
    for (int off = 1; off < 512; off <<= 1) {
        unsigned int add = (t >= off) ? sh[t - off] : 0u;
        __syncthreads();
        sh[t] += add;
        __syncthreads();
    }
    if (t < nb) boff[t] = sh[t] - v;
}

__global__ void scan3(unsigned int* __restrict__ rowptr, const unsigned int* __restrict__ boff,
                      unsigned int* __restrict__ cursor) {
    int i = blockIdx.x * 256 + threadIdx.x;
    if (i < N_NODES) {
        unsigned int r = rowptr[i] + boff[blockIdx.x];
        rowptr[i] = r;
        cursor[i] = r;
    }
    if (i == N_NODES) rowptr[N_NODES] = N_EDGES;
}

// ---------------- phase-1: load-balanced edge-chunk aggregation --------------
// R10 (post-mortem of R9's node-per-group scheme): degrees are Poisson(8), so
// block time was max over 16 groups (~16 edges) vs mean 8 -> ~1.8x idle lanes,
// plus a dependent srclist->gather chain each iteration.
// New scheme: the block's edge range [rowptr[b], rowptr[b+16]) is split into 16
// equal contiguous chunks, one per 16-lane group. srclist is prefetched 16
// edges at a time into lane registers (one round trip / 16 edges), broadcast
// via __shfl. CSR order keeps each chunk sorted by dst, so accumulation stays
// in registers and flushes to a shared fp32 accumulator (LDS atomics) only at
// node boundaries (~32 flushes/block). Flush addresses use a (jj+l)&7 rotation
// so the 16-lane flush is 2-way bank-aliased (free) instead of 4-way.
__device__ __forceinline__ void agg_phase16(const unsigned short* __restrict__ hb,
                                            const unsigned int* __restrict__ rowptr,
                                            const int* __restrict__ srclist,
                                            float* __restrict__ accf,
                                            unsigned int* __restrict__ smean,
                                            int blockrow) {
    const int tid = threadIdx.x;
    const int g = tid >> 4;          // group 0..15
    const int l = tid & 15;          // lane in group
    const int srcbase = (g & 3) << 4; // group's lane0 within its wave

    // zero the fp32 accumulator
    for (int i = tid; i < 16 * ACC_S; i += 256) accf[i] = 0.f;
    __syncthreads();

    unsigned int e0 = rowptr[blockrow];
    unsigned int e1 = rowptr[blockrow + 16];
    unsigned int nE = e1 - e0;
    unsigned int per = (nE + 15u) >> 4;
    unsigned int start = e0 + (unsigned int)g * per;
    unsigned int end = start + per;
    if (end > e1) end = e1;

    const uint4* hp = (const uint4*)hb;
    float f0 = 0.f, f1 = 0.f, f2 = 0.f, f3 = 0.f, f4 = 0.f, f5 = 0.f, f6 = 0.f, f7 = 0.f;
    int dcur = -1;

#define ACC8(U) { f0 += blo(U.x); f1 += bhi(U.x); f2 += blo(U.y); f3 += bhi(U.y); \
                  f4 += blo(U.z); f5 += bhi(U.z); f6 += blo(U.w); f7 += bhi(U.w); }
#define FLUSHA() { if (dcur >= 0) { float* ap = accf + dcur * ACC_S + l * 8; \
    atomicAdd(&ap[(0 + l) & 7], f0); atomicAdd(&ap[(1 + l) & 7], f1); \
    atomicAdd(&ap[(2 + l) & 7], f2); atomicAdd(&ap[(3 + l) & 7], f3); \
    atomicAdd(&ap[(4 + l) & 7], f4); atomicAdd(&ap[(5 + l) & 7], f5); \
    atomicAdd(&ap[(6 + l) & 7], f6); atomicAdd(&ap[(7 + l) & 7], f7); \
    f0 = f1 = f2 = f3 = f4 = f5 = f6 = f7 = 0.f; } }
#define EDGE(P, U) { int dd = (int)((P >> 17) & 15u); \
    if (dd != dcur) { FLUSHA(); dcur = dd; } ACC8(U); }

    for (unsigned int base = start; base < end; base += 16u) {
        unsigned int rem = end - base;
        int m = rem < 16u ? (int)rem : 16;
        unsigned int pk = 0u;
        if ((unsigned int)l < rem) pk = (unsigned int)srclist[base + (unsigned int)l];
        int j = 0;
        for (; j + 4 <= m; j += 4) {
            unsigned int p0 = (unsigned int)__shfl((int)pk, srcbase + j + 0);
            unsigned int p1 = (unsigned int)__shfl((int)pk, srcbase + j + 1);
            unsigned int p2 = (unsigned int)__shfl((int)pk, srcbase + j + 2);
            unsigned int p3 = (unsigned int)__shfl((int)pk, srcbase + j + 3);
            uint4 u0 = hp[(size_t)(p0 & 0x1FFFFu) * 16 + l];
            uint4 u1 = hp[(size_t)(p1 & 0x1FFFFu) * 16 + l];
            uint4 u2 = hp[(size_t)(p2 & 0x1FFFFu) * 16 + l];
            uint4 u3 = hp[(size_t)(p3 & 0x1FFFFu) * 16 + l];
            EDGE(p0, u0); EDGE(p1, u1); EDGE(p2, u2); EDGE(p3, u3);
        }
        for (; j < m; ++j) {
            unsigned int p0 = (unsigned int)__shfl((int)pk, srcbase + j);
            uint4 u0 = hp[(size_t)(p0 & 0x1FFFFu) * 16 + l];
            EDGE(p0, u0);
        }
    }
    FLUSHA();
#undef EDGE
#undef FLUSHA
#undef ACC8

    __syncthreads();

    // finalize: mean + bf16 pack into MFMA-A layout (node g, dims [l*8, l*8+8))
    {
        unsigned int b = rowptr[blockrow + g];
        unsigned int e = rowptr[blockrow + g + 1];
        unsigned int deg = e - b;
        float r = 1.0f / (float)(deg > 1u ? deg : 1u);
        const float* ap = accf + g * ACC_S + l * 8;
        float v0 = ap[(0 + l) & 7] * r;
        float v1 = ap[(1 + l) & 7] * r;
        float v2 = ap[(2 + l) & 7] * r;
        float v3 = ap[(3 + l) & 7] * r;
        float v4 = ap[(4 + l) & 7] * r;
        float v5 = ap[(5 + l) & 7] * r;
        float v6 = ap[(6 + l) & 7] * r;
        float v7 = ap[(7 + l) & 7] * r;
        uint4 o;
        o.x = (unsigned int)f2b(v0) | ((unsigned int)f2b(v1) << 16);
        o.y = (unsigned int)f2b(v2) | ((unsigned int)f2b(v3) << 16);
        o.z = (unsigned int)f2b(v4) | ((unsigned int)f2b(v5) << 16);
        o.w = (unsigned int)f2b(v6) | ((unsigned int)f2b(v7) << 16);
        *(uint4*)&smean[g * MROW + l * 4] = o;
    }
}

// ---------------- fused agg + GEMM L0/L1 + BN stats + bf16 C -----------------
// 16-row blocks, grid 6250 (= N/16). Phase 2: wave w handles cols [32w,32w+32)
// of all 16 rows (acc = 8 VGPRs).
__global__ void __launch_bounds__(256) gemm2f_k(const unsigned short* __restrict__ hb,
                                                const unsigned int* __restrict__ rowptr,
                                                const int* __restrict__ srclist,
                                                const unsigned short* __restrict__ Bp,
                                                unsigned short* __restrict__ outb,
                                                float* __restrict__ sums) {
    __shared__ float accf[16 * ACC_S];
    __shared__ unsigned int smean[16 * MROW];
    __shared__ float lds_s[128];
    __shared__ float lds_s2[128];
    int wave = threadIdx.x >> 6;
    int lane = threadIdx.x & 63;
    int quad = lane >> 4;
    int l15 = lane & 15;
    int blockrow = blockIdx.x * 16;

    if (threadIdx.x < 128) { lds_s[threadIdx.x] = 0.f; lds_s2[threadIdx.x] = 0.f; }

    agg_phase16(hb, rowptr, srclist, accf, smean, blockrow);
    __syncthreads();

    floatx4 acc[2];
    acc[0] = (floatx4){0.f, 0.f, 0.f, 0.f};
    acc[1] = (floatx4){0.f, 0.f, 0.f, 0.f};

    int r0 = blockrow + l15;   // always < N_NODES (exact division)

#pragma unroll
    for (int t = 0; t < 8; t++) {
        short8 a0;
        if (t < 4) {
            a0 = *(const short8*)&smean[l15 * MROW + t * 16 + quad * 4];
        } else {
            int koff = (t & 3) * 32 + quad * 8;
            a0 = *(const short8*)(hb + (size_t)r0 * 128 + koff);
        }
#pragma unroll
        for (int c = 0; c < 2; c++) {
            int cidx = wave * 2 + c;
            short8 bf = *(const short8*)(Bp + ((size_t)(t * 8 + cidx) * 64 + lane) * 8);
            acc[c] = __builtin_amdgcn_mfma_f32_16x16x32_bf16(a0, bf, acc[c], 0, 0, 0);
        }
    }

#pragma unroll
    for (int c = 0; c < 2; c++) {
        int col = wave * 32 + c * 16 + l15;
        float s = 0.f, s2 = 0.f;
#pragma unroll
        for (int r = 0; r < 4; r++) {
            int row = blockrow + quad * 4 + r;
            float v = acc[c][r];
            outb[(size_t)row * 128 + col] = f2b(v);
            s += v; s2 += v * v;
        }
        s += __shfl_xor(s, 16);  s += __shfl_xor(s, 32);
        s2 += __shfl_xor(s2, 16); s2 += __shfl_xor(s2, 32);
        if (quad == 0) {
            atomicAdd(&lds_s[col], s);
            atomicAdd(&lds_s2[col], s2);
        }
    }

    __syncthreads();
    if (threadIdx.x < 128) {
        int bank = blockIdx.x & (NBANK - 1);
        atomicAdd(&sums[bank * 256 + threadIdx.x], lds_s[threadIdx.x]);
        atomicAdd(&sums[bank * 256 + 128 + threadIdx.x], lds_s2[threadIdx.x]);
    }
}

// ---------------- fused agg + GEMM L2 (40 cols, bias, fp32 out) --------------
// 16-row blocks; waves 0-2 each own one 16-col tile (48 >= 40); wave 3 only
// helps in the gather phase.
__global__ void __launch_bounds__(256) gemm3f_k(const unsigned short* __restrict__ hb,
                                                const unsigned int* __restrict__ rowptr,
                                                const int* __restrict__ srclist,
                                                const unsigned short* __restrict__ Bp,
                                                const float* __restrict__ bias,
                                                float* __restrict__ out) {
    __shared__ float accf[16 * ACC_S];
    __shared__ unsigned int smean[16 * MROW];
    int wave = threadIdx.x >> 6;
    int lane = threadIdx.x & 63;
    int quad = lane >> 4;
    int l15 = lane & 15;
    int blockrow = blockIdx.x * 16;

    agg_phase16(hb, rowptr, srclist, accf, smean, blockrow);
    __syncthreads();

    if (wave >= 3) return;

    floatx4 acc = (floatx4){0.f, 0.f, 0.f, 0.f};
    int r0 = blockrow + l15;

#pragma unroll
    for (int t = 0; t < 8; t++) {
        short8 a0;
        if (t < 4) {
            a0 = *(const short8*)&smean[l15 * MROW + t * 16 + quad * 4];
        } else {
            int koff = (t & 3) * 32 + quad * 8;
            a0 = *(const short8*)(hb + (size_t)r0 * 128 + koff);
        }
        short8 bf = *(const short8*)(Bp + ((size_t)(t * 3 + wave) * 64 + lane) * 8);
        acc = __builtin_amdgcn_mfma_f32_16x16x32_bf16(a0, bf, acc, 0, 0, 0);
    }

    int col = wave * 16 + l15;
    if (col < 40) {
#pragma unroll
        for (int r = 0; r < 4; r++) {
            int row = blockrow + quad * 4 + r;
            out[(size_t)row * 40 + col] = acc[r] + bias[col];
        }
    }
}

// ---------------- BN finalize (reduce 32 banks) ------------------------------
__global__ void bn_finalize(const float* __restrict__ sums, const float* __restrict__ g,
                            const float* __restrict__ be, float* __restrict__ sc,
                            float* __restrict__ sh) {
    __shared__ float lds[256];
    int t = threadIdx.x;
    float s = 0.f;
#pragma unroll 8
    for (int bk = 0; bk < NBANK; bk++) s += sums[bk * 256 + t];
    lds[t] = s;
    __syncthreads();
    if (t < 128) {
        float inv_n = 1.0f / (float)N_NODES;
        float mu = lds[t] * inv_n;
        float var = lds[128 + t] * inv_n - mu * mu;
        float sf = g[t] * rsqrtf(var + EPS);
        sc[t] = sf;
        sh[t] = be[t] - mu * sf;
    }
}

// ---------------- BN apply: bf16 in -> bf16 out, 8 elems/thread --------------
__global__ void bn_apply(const unsigned int* __restrict__ Cb, const float* __restrict__ sc,
                         const float* __restrict__ sh, unsigned short* __restrict__ ho) {
    int i = blockIdx.x * 256 + threadIdx.x;  // one uint4 = 8 bf16
    if (i >= N_NODES * 16) return;
    uint4 v = ((const uint4*)Cb)[i];
    int c0 = (i * 8) & 127;
    uint4 o;
    float e0 = fmaxf(0.f, blo(v.x) * sc[c0 + 0] + sh[c0 + 0]);
    float e1 = fmaxf(0.f, bhi(v.x) * sc[c0 + 1] + sh[c0 + 1]);
    float e2 = fmaxf(0.f, blo(v.y) * sc[c0 + 2] + sh[c0 + 2]);
    float e3 = fmaxf(0.f, bhi(v.y) * sc[c0 + 3] + sh[c0 + 3]);
    float e4 = fmaxf(0.f, blo(v.z) * sc[c0 + 4] + sh[c0 + 4]);
    float e5 = fmaxf(0.f, bhi(v.z) * sc[c0 + 5] + sh[c0 + 5]);
    float e6 = fmaxf(0.f, blo(v.w) * sc[c0 + 6] + sh[c0 + 6]);
    float e7 = fmaxf(0.f, bhi(v.w) * sc[c0 + 7] + sh[c0 + 7]);
    o.x = (unsigned int)f2b(e0) | ((unsigned int)f2b(e1) << 16);
    o.y = (unsigned int)f2b(e2) | ((unsigned int)f2b(e3) << 16);
    o.z = (unsigned int)f2b(e4) | ((unsigned int)f2b(e5) << 16);
    o.w = (unsigned int)f2b(e6) | ((unsigned int)f2b(e7) << 16);
    ((uint4*)ho)[i] = o;
}

// ---------------- host ----------------
extern "C" void kernel_launch(void* const* d_in, const int* in_sizes, int n_in,
                              void* d_out, int out_size, void* d_ws, size_t ws_size,
                              hipStream_t stream) {
    const float* x   = (const float*)d_in[0];
    const int* ei    = (const int*)d_in[1];     // [2, E] int32: row 0 = src, row 1 = dst
    const float* Wl0 = (const float*)d_in[2];
    const float* Wr0 = (const float*)d_in[3];
    const float* Wl1 = (const float*)d_in[4];
    const float* Wr1 = (const float*)d_in[5];
    const float* Wl2 = (const float*)d_in[6];
    const float* Wr2 = (const float*)d_in[7];
    const float* b2  = (const float*)d_in[8];
    const float* g0  = (const float*)d_in[9];
    const float* be0 = (const float*)d_in[10];
    const float* g1  = (const float*)d_in[11];
    const float* be1 = (const float*)d_in[12];

    char* ws = (char*)d_ws;
    size_t off = 0;
    auto alloc = [&](size_t bytes) -> void* {
        void* p = ws + off;
        off += (bytes + 4095) & ~(size_t)4095;
        return p;
    };

    const size_t NB16 = (size_t)N_NODES * 128 * 2;  // 25.6 MB bf16 feature buffer
    unsigned short* xb   = (unsigned short*)alloc(NB16);   // x in bf16; reused as h2
    unsigned short* h1   = (unsigned short*)alloc(NB16);
    unsigned short* C    = (unsigned short*)alloc(NB16);   // pre-BN bf16
    unsigned int* cnt    = (unsigned int*)alloc((size_t)N_NODES * 4);
    unsigned int* rowptr = (unsigned int*)alloc((size_t)(N_NODES + 1) * 4);
    unsigned int* cursor = (unsigned int*)alloc((size_t)N_NODES * 4);
    int* srclist         = (int*)alloc((size_t)N_EDGES * 4);
    unsigned int* ebuf   = (unsigned int*)alloc((size_t)N_EDGES * 4);
    unsigned int* bhist  = (unsigned int*)alloc(8 * HB_BLOCKS * 4);
    unsigned int* bsum   = (unsigned int*)alloc(512 * 4);
    unsigned int* boff   = (unsigned int*)alloc(512 * 4);
    float* sums0         = (float*)alloc(NBANK * 256 * 4);   // contiguous with sums1
    float* sums1         = (float*)alloc(NBANK * 256 * 4);
    float* sc            = (float*)alloc(128 * 4);
    float* sh            = (float*)alloc(128 * 4);
    unsigned short* W0p  = (unsigned short*)alloc(8 * 8 * 64 * 8 * 2);
    unsigned short* W1p  = (unsigned short*)alloc(8 * 8 * 64 * 8 * 2);
    unsigned short* W2p  = (unsigned short*)alloc(3 * 8 * 64 * 8 * 2);
    unsigned short* h2   = xb;  // alias: xb dead after layer-0 GEMM

    const int* srcp = ei;
    const int* dstp = ei + N_EDGES;

    // ---- prep (both BN sums buffers zeroed up front; none mid-pipeline) ----
    hipMemsetAsync(cnt, 0, (size_t)N_NODES * 4, stream);
    hipMemsetAsync(sums0, 0, (size_t)2 * NBANK * 256 * 4, stream);  // sums0+sums1
    cvt_f32_bf16<<<12500, 256, 0, stream>>>(x, xb, N_NODES * 32);
    pack_w<<<(8 * 4096 + 255) / 256, 256, 0, stream>>>(Wl0, Wr0, W0p, 128, 8);
    pack_w<<<(8 * 4096 + 255) / 256, 256, 0, stream>>>(Wl1, Wr1, W1p, 128, 8);
    pack_w<<<(3 * 4096 + 255) / 256, 256, 0, stream>>>(Wl2, Wr2, W2p, 40, 3);

    // ---- CSR (two-level counting sort) ----
    hist_k<<<HB_BLOCKS, 256, 0, stream>>>(dstp, cnt, bhist);
    scan1<<<391, 256, 0, stream>>>(cnt, rowptr, bsum);
    scan2<<<1, 512, 0, stream>>>(bsum, boff, 391);
    scan3<<<391, 256, 0, stream>>>(rowptr, boff, cursor);
    bscan<<<1, 256, 0, stream>>>(bhist);
    bscatter<<<HB_BLOCKS, 256, 0, stream>>>(srcp, dstp, bhist, ebuf);
    cscatter<<<8 * CS_GPB, 256, 0, stream>>>(ebuf, rowptr, cursor, srclist);

    // ---- layer 0 (fused agg+gemm, 16-row blocks) ----
    gemm2f_k<<<6250, 256, 0, stream>>>(xb, rowptr, srclist, W0p, C, sums0);
    bn_finalize<<<1, 256, 0, stream>>>(sums0, g0, be0, sc, sh);
    bn_apply<<<6250, 256, 0, stream>>>((const unsigned int*)C, sc, sh, h1);

    // ---- layer 1 ----
    gemm2f_k<<<6250, 256, 0, stream>>>(h1, rowptr, srclist, W1p, C, sums1);
    bn_finalize<<<1, 256, 0, stream>>>(sums1, g1, be1, sc, sh);
    bn_apply<<<6250, 256, 0, stream>>>((const unsigned int*)C, sc, sh, h2);

    // ---- layer 2 (writes d_out, fp32 [N,40]) ----
    gemm3f_k<<<6250, 256, 0, stream>>>(h2, rowptr, srclist, W2p, b2, (float*)d_out);

    (void)in_sizes; (void)n_in; (void)out_size; (void)ws_size;
}

// Round 2
// 449.051 us; speedup vs baseline: 1.4380x; 1.4380x over previous
//
#include <hip/hip_runtime.h>
#include <hip/hip_bf16.h>

#define N_NODES 100000
#define N_EDGES 800000
#define EPS 1e-5f
#define NBANK 32
#define HB_BLOCKS 256
#define HB_PER 3125          // 256 * 3125 = 800000 exactly
#define CS_GPB 64            // cscatter blocks per coarse bucket
#define BUCKET_N 12500       // 8 * 12500 = 100000 exactly
#define MROW 68              // LDS mean row stride in dwords (64 + 4 pad)

typedef __attribute__((ext_vector_type(8))) short short8;
typedef __attribute__((ext_vector_type(4))) float floatx4;

__device__ __forceinline__ unsigned short f2b(float f) {
    unsigned int u = __float_as_uint(f);
    u = (u + 0x7fffu + ((u >> 16) & 1u)) >> 16;   // round-to-nearest-even
    return (unsigned short)u;
}
__device__ __forceinline__ float blo(unsigned int u) { return __uint_as_float(u << 16); }
__device__ __forceinline__ float bhi(unsigned int u) { return __uint_as_float(u & 0xffff0000u); }

// ---------------- elementwise convert fp32 -> bf16 (x input) ----------------
__global__ void cvt_f32_bf16(const float* __restrict__ x, unsigned short* __restrict__ o, int n4) {
    int i = blockIdx.x * blockDim.x + threadIdx.x;
    if (i >= n4) return;
    float4 v = ((const float4*)x)[i];
    ushort4 r;
    r.x = f2b(v.x); r.y = f2b(v.y); r.z = f2b(v.z); r.w = f2b(v.w);
    ((ushort4*)o)[i] = r;
}

// ---------------- pack [Wl;Wr] (K=256 x Hreal) into MFMA B-fragment order ----
__global__ void pack_w(const float* __restrict__ Wl, const float* __restrict__ Wr,
                       unsigned short* __restrict__ out, int Hreal, int NCT) {
    int tid = blockIdx.x * blockDim.x + threadIdx.x;
    int total = NCT * 8 * 64 * 8;
    if (tid >= total) return;
    int i = tid & 7;
    int lane = (tid >> 3) & 63;
    int q = tid >> 9;
    int c = q % NCT;
    int t = q / NCT;
    int k = t * 32 + (lane >> 4) * 8 + i;
    int n = c * 16 + (lane & 15);
    float v = 0.f;
    if (n < Hreal) v = (k < 128) ? Wl[k * Hreal + n] : Wr[(k - 128) * Hreal + n];
    out[tid] = f2b(v);
}

// ---------------- CSR build: two-level counting sort -------------------------
__global__ void __launch_bounds__(256) hist_k(const int* __restrict__ dst,
                                              unsigned int* __restrict__ cnt,
                                              unsigned int* __restrict__ bhist) {
    __shared__ unsigned int lh[8];
    if (threadIdx.x < 8) lh[threadIdx.x] = 0;
    __syncthreads();
    int start = blockIdx.x * HB_PER;
    for (int i = threadIdx.x; i < HB_PER; i += 256) {
        int d = dst[start + i];
        atomicAdd(&cnt[d], 1u);
        atomicAdd(&lh[(unsigned int)d / BUCKET_N], 1u);
    }
    __syncthreads();
    if (threadIdx.x < 8) bhist[threadIdx.x * HB_BLOCKS + blockIdx.x] = lh[threadIdx.x];
}

__global__ void bscan(unsigned int* __restrict__ A) {
    __shared__ unsigned int part[256];
    int t = threadIdx.x;
    unsigned int v[8];
    unsigned int s = 0;
#pragma unroll
    for (int i = 0; i < 8; i++) { v[i] = A[t * 8 + i]; s += v[i]; }
    part[t] = s; __syncthreads();
    for (int off = 1; off < 256; off <<= 1) {
        unsigned int add = (t >= off) ? part[t - off] : 0u;
        __syncthreads();
        part[t] += add;
        __syncthreads();
    }
    unsigned int base = part[t] - s;  // exclusive
#pragma unroll
    for (int i = 0; i < 8; i++) { unsigned int old = v[i]; A[t * 8 + i] = base; base += old; }
}

__global__ void __launch_bounds__(256) bscatter(const int* __restrict__ src,
                                                const int* __restrict__ dst,
                                                const unsigned int* __restrict__ boffs,
                                                unsigned int* __restrict__ ebuf) {
    __shared__ unsigned int cur[8];
    if (threadIdx.x < 8) cur[threadIdx.x] = boffs[threadIdx.x * HB_BLOCKS + blockIdx.x];
    __syncthreads();
    int start = blockIdx.x * HB_PER;
    for (int i = threadIdx.x; i < HB_PER; i += 256) {
        int d = dst[start + i];
        int s = src[start + i];
        unsigned int b = (unsigned int)d / BUCKET_N;
        unsigned int dl = (unsigned int)d - b * BUCKET_N;
        unsigned int pos = atomicAdd(&cur[b], 1u);
        ebuf[pos] = (unsigned int)s | (dl << 17);
    }
}

__global__ void __launch_bounds__(256) cscatter(const unsigned int* __restrict__ ebuf,
                                                const unsigned int* __restrict__ rowptr,
                                                unsigned int* __restrict__ cursor,
                                                int* __restrict__ srclist) {
    int g = blockIdx.x & 7;
    int gblk = blockIdx.x >> 3;
    unsigned int estart = rowptr[g * BUCKET_N];
    unsigned int eend = (g == 7) ? N_EDGES : rowptr[(g + 1) * BUCKET_N];
    unsigned int nume = eend - estart;
    unsigned int per = (nume + CS_GPB - 1) / CS_GPB;
    unsigned int s0 = estart + gblk * per;
    unsigned int s1 = s0 + per; if (s1 > eend) s1 = eend;
    unsigned int nodebase = g * BUCKET_N;
    for (unsigned int i = s0 + threadIdx.x; i < s1; i += 256) {
        unsigned int p = ebuf[i];
        unsigned int s = p & 0x1FFFFu;
        unsigned int node = nodebase + (p >> 17);
        unsigned int pos = atomicAdd(&cursor[node], 1u);
        srclist[pos] = (int)s;
    }
}

__global__ void scan1(const unsigned int* __restrict__ cnt, unsigned int* __restrict__ rowptr,
                      unsigned int* __restrict__ bsum) {
    __shared__ unsigned int sh[256];
    int t = threadIdx.x;
    int i = blockIdx.x * 256 + t;
    unsigned int v = (i < N_NODES) ? cnt[i] : 0u;
    sh[t] = v; __syncthreads();
    for (int off = 1; off < 256; off <<= 1) {
        unsigned int add = (t >= off) ? sh[t - off] : 0u;
        __syncthreads();
        sh[t] += add;
        __syncthreads();
    }
    if (i < N_NODES) rowptr[i] = sh[t] - v;  // exclusive within block
    if (t == 255) bsum[blockIdx.x] = sh[255];
}

__global__ void scan2(const unsigned int* __restrict__ bsum, unsigned int* __restrict__ boff, int nb) {
    __shared__ unsigned int sh[512];
    int t = threadIdx.x;
    unsigned int v = (t < nb) ? bsum[t] : 0u;
    sh[t] = v; __syncthreads();
    for (int off = 1; off < 512; off <<= 1) {
        unsigned int add = (t >= off) ? sh[t - off] : 0u;
        __syncthreads();
        sh[t] += add;
        __syncthreads();
    }
    if (t < nb) boff[t] = sh[t] - v;
}

__global__ void scan3(unsigned int* __restrict__ rowptr, const unsigned int* __restrict__ boff,
                      unsigned int* __restrict__ cursor) {
    int i = blockIdx.x * 256 + threadIdx.x;
    if (i < N_NODES) {
        unsigned int r = rowptr[i] + boff[blockIdx.x];
        rowptr[i] = r;
        cursor[i] = r;
    }
    if (i == N_NODES) rowptr[N_NODES] = N_EDGES;
}

// ---------------- degree-balanced node permutation (R11) ---------------------
// Counting sort of node ids by degree (64 bins, clamp). Blocks then take 16
// consecutive perm entries -> all groups in a block/wave have near-equal
// degree -> no max-over-Poisson wave imbalance in the agg phase.
__global__ void __launch_bounds__(256) deg_hist(const unsigned int* __restrict__ cnt,
                                                unsigned int* __restrict__ dh) {
    __shared__ unsigned int lh[64];
    if (threadIdx.x < 64) lh[threadIdx.x] = 0;
    __syncthreads();
    int i = blockIdx.x * 256 + threadIdx.x;
    if (i < N_NODES) {
        unsigned int d = cnt[i]; if (d > 63u) d = 63u;
        atomicAdd(&lh[d], 1u);
    }
    __syncthreads();
    if (threadIdx.x < 64 && lh[threadIdx.x]) atomicAdd(&dh[threadIdx.x], lh[threadIdx.x]);
}

__global__ void deg_scan(unsigned int* __restrict__ dh, unsigned int* __restrict__ dcur) {
    int t = threadIdx.x;  // 64 threads
    unsigned int v = dh[t];
    unsigned int s = v;
#pragma unroll
    for (int off = 1; off < 64; off <<= 1) {
        unsigned int n = __shfl_up(s, off);
        if (t >= off) s += n;
    }
    unsigned int ex = s - v;   // exclusive
    dh[t] = ex;
    dcur[t] = ex;
}

__global__ void __launch_bounds__(256) deg_scatter(const unsigned int* __restrict__ cnt,
                                                   unsigned int* __restrict__ dcur,
                                                   int* __restrict__ perm) {
    __shared__ unsigned int lh[64];
    __shared__ unsigned int lbase[64];
    int t = threadIdx.x;
    if (t < 64) lh[t] = 0;
    __syncthreads();
    int i = blockIdx.x * 256 + t;
    unsigned int d = 0, loc = 0;
    bool valid = i < N_NODES;
    if (valid) {
        d = cnt[i]; if (d > 63u) d = 63u;
        loc = atomicAdd(&lh[d], 1u);   // LDS atomic: cheap local rank
    }
    __syncthreads();
    if (t < 64 && lh[t]) lbase[t] = atomicAdd(&dcur[t], lh[t]);  // 1 global atomic/bin/block
    __syncthreads();
    if (valid) perm[lbase[d] + loc] = i;
}

// ---------------- phase-1: aggregate 16 nodes, 1 node/group ------------------
// R11 (post-mortem of R10's edge-chunk scheme: per-edge branch diverged across
// the 4 groups in a wave + 8 LDS atomics per flush -> 2.7x regression).
// Back to R9's divergence-free register accumulation, plus:
//  - unroll-8 first batches: 32 outstanding 16B gathers/wave (Little's law on
//    R9: 16 outst * 16B / ~600cy * 32 waves ~= 2.5 TB/s == measured ceiling;
//    doubling outstanding is the direct lever)
//  - node = pblk[group] (degree-sorted permutation) -> equal trip counts
//    across groups -> no masked-lane waste, no remainder divergence.
__device__ __forceinline__ void agg_phase16(const unsigned short* __restrict__ hb,
                                            const unsigned int* __restrict__ rowptr,
                                            const int* __restrict__ srclist,
                                            unsigned int* __restrict__ smean,
                                            const int* __restrict__ pblk,
                                            int wave, int g, int l) {
    const uint4* hp = (const uint4*)hb;
    int nl = wave * 4 + g;
    int node = pblk[nl];
    float f0 = 0.f, f1 = 0.f, f2 = 0.f, f3 = 0.f, f4 = 0.f, f5 = 0.f, f6 = 0.f, f7 = 0.f;
    unsigned int b = rowptr[node], e = rowptr[node + 1];
    unsigned int p = b;
#define ACC8(U) { f0 += blo(U.x); f1 += bhi(U.x); f2 += blo(U.y); f3 += bhi(U.y); \
                  f4 += blo(U.z); f5 += bhi(U.z); f6 += blo(U.w); f7 += bhi(U.w); }
    for (; p + 8 <= e; p += 8) {
        int s0 = srclist[p];     int s1 = srclist[p + 1];
        int s2 = srclist[p + 2]; int s3 = srclist[p + 3];
        int s4 = srclist[p + 4]; int s5 = srclist[p + 5];
        int s6 = srclist[p + 6]; int s7 = srclist[p + 7];
        uint4 u0 = hp[(size_t)s0 * 16 + l];
        uint4 u1 = hp[(size_t)s1 * 16 + l];
        uint4 u2 = hp[(size_t)s2 * 16 + l];
        uint4 u3 = hp[(size_t)s3 * 16 + l];
        uint4 u4 = hp[(size_t)s4 * 16 + l];
        uint4 u5 = hp[(size_t)s5 * 16 + l];
        uint4 u6 = hp[(size_t)s6 * 16 + l];
        uint4 u7 = hp[(size_t)s7 * 16 + l];
        ACC8(u0); ACC8(u1); ACC8(u2); ACC8(u3);
        ACC8(u4); ACC8(u5); ACC8(u6); ACC8(u7);
    }
    if (p + 4 <= e) {
        int s0 = srclist[p];     int s1 = srclist[p + 1];
        int s2 = srclist[p + 2]; int s3 = srclist[p + 3];
        uint4 u0 = hp[(size_t)s0 * 16 + l];
        uint4 u1 = hp[(size_t)s1 * 16 + l];
        uint4 u2 = hp[(size_t)s2 * 16 + l];
        uint4 u3 = hp[(size_t)s3 * 16 + l];
        ACC8(u0); ACC8(u1); ACC8(u2); ACC8(u3);
        p += 4;
    }
    if (p + 2 <= e) {
        int s0 = srclist[p];
        int s1 = srclist[p + 1];
        uint4 u0 = hp[(size_t)s0 * 16 + l];
        uint4 u1 = hp[(size_t)s1 * 16 + l];
        ACC8(u0); ACC8(u1);
        p += 2;
    }
    if (p < e) {
        int s0 = srclist[p];
        uint4 u0 = hp[(size_t)s0 * 16 + l];
        ACC8(u0);
    }
#undef ACC8
    unsigned int deg = e - b;
    float r = 1.0f / (float)(deg > 1u ? deg : 1u);
    uint4 o;
    o.x = (unsigned int)f2b(f0 * r) | ((unsigned int)f2b(f1 * r) << 16);
    o.y = (unsigned int)f2b(f2 * r) | ((unsigned int)f2b(f3 * r) << 16);
    o.z = (unsigned int)f2b(f4 * r) | ((unsigned int)f2b(f5 * r) << 16);
    o.w = (unsigned int)f2b(f6 * r) | ((unsigned int)f2b(f7 * r) << 16);
    *(uint4*)&smean[nl * MROW + l * 4] = o;
}

// ---------------- fused agg + GEMM L0/L1 + BN stats + bf16 C -----------------
// 16-row blocks, grid 6250 (= N/16); block's rows are perm[16b..16b+16).
// Phase 2: wave w handles cols [32w,32w+32) of all 16 rows (acc = 8 VGPRs).
// __launch_bounds__(256,8): pin 8 blocks/CU (VGPR <= 64) so the unroll-8
// in-flight loads can't tip the occupancy cliff.
__global__ void __launch_bounds__(256, 8) gemm2f_k(const unsigned short* __restrict__ hb,
                                                   const unsigned int* __restrict__ rowptr,
                                                   const int* __restrict__ srclist,
                                                   const int* __restrict__ perm,
                                                   const unsigned short* __restrict__ Bp,
                                                   unsigned short* __restrict__ outb,
                                                   float* __restrict__ sums) {
    __shared__ unsigned int smean[16 * MROW];
    __shared__ float lds_s[128];
    __shared__ float lds_s2[128];
    __shared__ int pblk[16];
    int wave = threadIdx.x >> 6;
    int lane = threadIdx.x & 63;
    int quad = lane >> 4;
    int l15 = lane & 15;

    if (threadIdx.x < 128) { lds_s[threadIdx.x] = 0.f; lds_s2[threadIdx.x] = 0.f; }
    if (threadIdx.x < 16) pblk[threadIdx.x] = perm[blockIdx.x * 16 + threadIdx.x];
    __syncthreads();

    agg_phase16(hb, rowptr, srclist, smean, pblk, wave, quad, l15);
    __syncthreads();

    floatx4 acc[2];
    acc[0] = (floatx4){0.f, 0.f, 0.f, 0.f};
    acc[1] = (floatx4){0.f, 0.f, 0.f, 0.f};

    int r0 = pblk[l15];

#pragma unroll
    for (int t = 0; t < 8; t++) {
        short8 a0;
        if (t < 4) {
            a0 = *(const short8*)&smean[l15 * MROW + t * 16 + quad * 4];
        } else {
            int koff = (t & 3) * 32 + quad * 8;
            a0 = *(const short8*)(hb + (size_t)r0 * 128 + koff);
        }
#pragma unroll
        for (int c = 0; c < 2; c++) {
            int cidx = wave * 2 + c;
            short8 bf = *(const short8*)(Bp + ((size_t)(t * 8 + cidx) * 64 + lane) * 8);
            acc[c] = __builtin_amdgcn_mfma_f32_16x16x32_bf16(a0, bf, acc[c], 0, 0, 0);
        }
    }

#pragma unroll
    for (int c = 0; c < 2; c++) {
        int col = wave * 32 + c * 16 + l15;
        float s = 0.f, s2 = 0.f;
#pragma unroll
        for (int r = 0; r < 4; r++) {
            int row = pblk[quad * 4 + r];
            float v = acc[c][r];
            outb[(size_t)row * 128 + col] = f2b(v);
            s += v; s2 += v * v;
        }
        s += __shfl_xor(s, 16);  s += __shfl_xor(s, 32);
        s2 += __shfl_xor(s2, 16); s2 += __shfl_xor(s2, 32);
        if (quad == 0) {
            atomicAdd(&lds_s[col], s);
            atomicAdd(&lds_s2[col], s2);
        }
    }

    __syncthreads();
    if (threadIdx.x < 128) {
        int bank = blockIdx.x & (NBANK - 1);
        atomicAdd(&sums[bank * 256 + threadIdx.x], lds_s[threadIdx.x]);
        atomicAdd(&sums[bank * 256 + 128 + threadIdx.x], lds_s2[threadIdx.x]);
    }
}

// ---------------- fused agg + GEMM L2 (40 cols, bias, fp32 out) --------------
// 16-row blocks; waves 0-2 each own one 16-col tile (48 >= 40); wave 3 only
// helps in the gather phase.
__global__ void __launch_bounds__(256, 8) gemm3f_k(const unsigned short* __restrict__ hb,
                                                   const unsigned int* __restrict__ rowptr,
                                                   const int* __restrict__ srclist,
                                                   const int* __restrict__ perm,
                                                   const unsigned short* __restrict__ Bp,
                                                   const float* __restrict__ bias,
                                                   float* __restrict__ out) {
    __shared__ unsigned int smean[16 * MROW];
    __shared__ int pblk[16];
    int wave = threadIdx.x >> 6;
    int lane = threadIdx.x & 63;
    int quad = lane >> 4;
    int l15 = lane & 15;

    if (threadIdx.x < 16) pblk[threadIdx.x] = perm[blockIdx.x * 16 + threadIdx.x];
    __syncthreads();

    agg_phase16(hb, rowptr, srclist, smean, pblk, wave, quad, l15);
    __syncthreads();

    if (wave >= 3) return;

    floatx4 acc = (floatx4){0.f, 0.f, 0.f, 0.f};
    int r0 = pblk[l15];

#pragma unroll
    for (int t = 0; t < 8; t++) {
        short8 a0;
        if (t < 4) {
            a0 = *(const short8*)&smean[l15 * MROW + t * 16 + quad * 4];
        } else {
            int koff = (t & 3) * 32 + quad * 8;
            a0 = *(const short8*)(hb + (size_t)r0 * 128 + koff);
        }
        short8 bf = *(const short8*)(Bp + ((size_t)(t * 3 + wave) * 64 + lane) * 8);
        acc = __builtin_amdgcn_mfma_f32_16x16x32_bf16(a0, bf, acc, 0, 0, 0);
    }

    int col = wave * 16 + l15;
    if (col < 40) {
#pragma unroll
        for (int r = 0; r < 4; r++) {
            int row = pblk[quad * 4 + r];
            out[(size_t)row * 40 + col] = acc[r] + bias[col];
        }
    }
}

// ---------------- BN finalize (reduce 32 banks) ------------------------------
__global__ void bn_finalize(const float* __restrict__ sums, const float* __restrict__ g,
                            const float* __restrict__ be, float* __restrict__ sc,
                            float* __restrict__ sh) {
    __shared__ float lds[256];
    int t = threadIdx.x;
    float s = 0.f;
#pragma unroll 8
    for (int bk = 0; bk < NBANK; bk++) s += sums[bk * 256 + t];
    lds[t] = s;
    __syncthreads();
    if (t < 128) {
        float inv_n = 1.0f / (float)N_NODES;
        float mu = lds[t] * inv_n;
        float var = lds[128 + t] * inv_n - mu * mu;
        float sf = g[t] * rsqrtf(var + EPS);
        sc[t] = sf;
        sh[t] = be[t] - mu * sf;
    }
}

// ---------------- BN apply: bf16 in -> bf16 out, 8 elems/thread --------------
__global__ void bn_apply(const unsigned int* __restrict__ Cb, const float* __restrict__ sc,
                         const float* __restrict__ sh, unsigned short* __restrict__ ho) {
    int i = blockIdx.x * 256 + threadIdx.x;  // one uint4 = 8 bf16
    if (i >= N_NODES * 16) return;
    uint4 v = ((const uint4*)Cb)[i];
    int c0 = (i * 8) & 127;
    uint4 o;
    float e0 = fmaxf(0.f, blo(v.x) * sc[c0 + 0] + sh[c0 + 0]);
    float e1 = fmaxf(0.f, bhi(v.x) * sc[c0 + 1] + sh[c0 + 1]);
    float e2 = fmaxf(0.f, blo(v.y) * sc[c0 + 2] + sh[c0 + 2]);
    float e3 = fmaxf(0.f, bhi(v.y) * sc[c0 + 3] + sh[c0 + 3]);
    float e4 = fmaxf(0.f, blo(v.z) * sc[c0 + 4] + sh[c0 + 4]);
    float e5 = fmaxf(0.f, bhi(v.z) * sc[c0 + 5] + sh[c0 + 5]);
    float e6 = fmaxf(0.f, blo(v.w) * sc[c0 + 6] + sh[c0 + 6]);
    float e7 = fmaxf(0.f, bhi(v.w) * sc[c0 + 7] + sh[c0 + 7]);
    o.x = (unsigned int)f2b(e0) | ((unsigned int)f2b(e1) << 16);
    o.y = (unsigned int)f2b(e2) | ((unsigned int)f2b(e3) << 16);
    o.z = (unsigned int)f2b(e4) | ((unsigned int)f2b(e5) << 16);
    o.w = (unsigned int)f2b(e6) | ((unsigned int)f2b(e7) << 16);
    ((uint4*)ho)[i] = o;
}

// ---------------- host ----------------
extern "C" void kernel_launch(void* const* d_in, const int* in_sizes, int n_in,
                              void* d_out, int out_size, void* d_ws, size_t ws_size,
                              hipStream_t stream) {
    const float* x   = (const float*)d_in[0];
    const int* ei    = (const int*)d_in[1];     // [2, E] int32: row 0 = src, row 1 = dst
    const float* Wl0 = (const float*)d_in[2];
    const float* Wr0 = (const float*)d_in[3];
    const float* Wl1 = (const float*)d_in[4];
    const float* Wr1 = (const float*)d_in[5];
    const float* Wl2 = (const float*)d_in[6];
    const float* Wr2 = (const float*)d_in[7];
    const float* b2  = (const float*)d_in[8];
    const float* g0  = (const float*)d_in[9];
    const float* be0 = (const float*)d_in[10];
    const float* g1  = (const float*)d_in[11];
    const float* be1 = (const float*)d_in[12];

    char* ws = (char*)d_ws;
    size_t off = 0;
    auto alloc = [&](size_t bytes) -> void* {
        void* p = ws + off;
        off += (bytes + 4095) & ~(size_t)4095;
        return p;
    };

    const size_t NB16 = (size_t)N_NODES * 128 * 2;  // 25.6 MB bf16 feature buffer
    unsigned short* xb   = (unsigned short*)alloc(NB16);   // x in bf16; reused as h2
    unsigned short* h1   = (unsigned short*)alloc(NB16);
    unsigned short* C    = (unsigned short*)alloc(NB16);   // pre-BN bf16
    unsigned int* cnt    = (unsigned int*)alloc((size_t)N_NODES * 4);
    unsigned int* rowptr = (unsigned int*)alloc((size_t)(N_NODES + 1) * 4);
    unsigned int* cursor = (unsigned int*)alloc((size_t)N_NODES * 4);
    int* srclist         = (int*)alloc((size_t)N_EDGES * 4);
    unsigned int* ebuf   = (unsigned int*)alloc((size_t)N_EDGES * 4);
    unsigned int* bhist  = (unsigned int*)alloc(8 * HB_BLOCKS * 4);
    unsigned int* bsum   = (unsigned int*)alloc(512 * 4);
    unsigned int* boff   = (unsigned int*)alloc(512 * 4);
    float* sums0         = (float*)alloc(NBANK * 256 * 4);   // contiguous with sums1
    float* sums1         = (float*)alloc(NBANK * 256 * 4);
    float* sc            = (float*)alloc(128 * 4);
    float* sh            = (float*)alloc(128 * 4);
    unsigned short* W0p  = (unsigned short*)alloc(8 * 8 * 64 * 8 * 2);
    unsigned short* W1p  = (unsigned short*)alloc(8 * 8 * 64 * 8 * 2);
    unsigned short* W2p  = (unsigned short*)alloc(3 * 8 * 64 * 8 * 2);
    unsigned int* dh     = (unsigned int*)alloc(64 * 4);
    unsigned int* dcur   = (unsigned int*)alloc(64 * 4);
    int* perm            = (int*)alloc((size_t)N_NODES * 4);
    unsigned short* h2   = xb;  // alias: xb dead after layer-0 GEMM

    const int* srcp = ei;
    const int* dstp = ei + N_EDGES;

    // ---- prep (both BN sums buffers zeroed up front; none mid-pipeline) ----
    hipMemsetAsync(cnt, 0, (size_t)N_NODES * 4, stream);
    hipMemsetAsync(dh, 0, 64 * 4, stream);
    hipMemsetAsync(sums0, 0, (size_t)2 * NBANK * 256 * 4, stream);  // sums0+sums1
    cvt_f32_bf16<<<12500, 256, 0, stream>>>(x, xb, N_NODES * 32);
    pack_w<<<(8 * 4096 + 255) / 256, 256, 0, stream>>>(Wl0, Wr0, W0p, 128, 8);
    pack_w<<<(8 * 4096 + 255) / 256, 256, 0, stream>>>(Wl1, Wr1, W1p, 128, 8);
    pack_w<<<(3 * 4096 + 255) / 256, 256, 0, stream>>>(Wl2, Wr2, W2p, 40, 3);

    // ---- CSR (two-level counting sort) ----
    hist_k<<<HB_BLOCKS, 256, 0, stream>>>(dstp, cnt, bhist);
    scan1<<<391, 256, 0, stream>>>(cnt, rowptr, bsum);
    scan2<<<1, 512, 0, stream>>>(bsum, boff, 391);
    scan3<<<391, 256, 0, stream>>>(rowptr, boff, cursor);
    bscan<<<1, 256, 0, stream>>>(bhist);
    bscatter<<<HB_BLOCKS, 256, 0, stream>>>(srcp, dstp, bhist, ebuf);
    cscatter<<<8 * CS_GPB, 256, 0, stream>>>(ebuf, rowptr, cursor, srclist);

    // ---- degree-balanced permutation (uses cnt; independent of scan chain) --
    deg_hist<<<391, 256, 0, stream>>>(cnt, dh);
    deg_scan<<<1, 64, 0, stream>>>(dh, dcur);
    deg_scatter<<<391, 256, 0, stream>>>(cnt, dcur, perm);

    // ---- layer 0 (fused agg+gemm, 16-row blocks) ----
    gemm2f_k<<<6250, 256, 0, stream>>>(xb, rowptr, srclist, perm, W0p, C, sums0);
    bn_finalize<<<1, 256, 0, stream>>>(sums0, g0, be0, sc, sh);
    bn_apply<<<6250, 256, 0, stream>>>((const unsigned int*)C, sc, sh, h1);

    // ---- layer 1 ----
    gemm2f_k<<<6250, 256, 0, stream>>>(h1, rowptr, srclist, perm, W1p, C, sums1);
    bn_finalize<<<1, 256, 0, stream>>>(sums1, g1, be1, sc, sh);
    bn_apply<<<6250, 256, 0, stream>>>((const unsigned int*)C, sc, sh, h2);

    // ---- layer 2 (writes d_out, fp32 [N,40]) ----
    gemm3f_k<<<6250, 256, 0, stream>>>(h2, rowptr, srclist, perm, W2p, b2, (float*)d_out);

    (void)in_sizes; (void)n_in; (void)out_size; (void)ws_size;
}

// Round 3
// 441.301 us; speedup vs baseline: 1.4633x; 1.0176x over previous
//
#include <hip/hip_runtime.h>
#include <hip/hip_bf16.h>

#define N_NODES 100000
#define N_EDGES 800000
#define EPS 1e-5f
#define NBANK 32
#define HB_BLOCKS 256
#define HB_PER 3125          // 256 * 3125 = 800000 exactly
#define CS_GPB 64            // cscatter blocks per coarse bucket
#define BUCKET_N 12500       // 8 * 12500 = 100000 exactly
#define MROW 68              // LDS mean row stride in dwords (64 + 4 pad)

typedef __attribute__((ext_vector_type(8))) short short8;
typedef __attribute__((ext_vector_type(4))) float floatx4;

__device__ __forceinline__ unsigned short f2b(float f) {
    unsigned int u = __float_as_uint(f);
    u = (u + 0x7fffu + ((u >> 16) & 1u)) >> 16;   // round-to-nearest-even
    return (unsigned short)u;
}
__device__ __forceinline__ float blo(unsigned int u) { return __uint_as_float(u << 16); }
__device__ __forceinline__ float bhi(unsigned int u) { return __uint_as_float(u & 0xffff0000u); }

// ---------------- elementwise convert fp32 -> bf16 (x input) ----------------
__global__ void cvt_f32_bf16(const float* __restrict__ x, unsigned short* __restrict__ o, int n4) {
    int i = blockIdx.x * blockDim.x + threadIdx.x;
    if (i >= n4) return;
    float4 v = ((const float4*)x)[i];
    ushort4 r;
    r.x = f2b(v.x); r.y = f2b(v.y); r.z = f2b(v.z); r.w = f2b(v.w);
    ((ushort4*)o)[i] = r;
}

// ---------------- pack [Wl;Wr] (K=256 x Hreal) into MFMA B-fragment order ----
__global__ void pack_w(const float* __restrict__ Wl, const float* __restrict__ Wr,
                       unsigned short* __restrict__ out, int Hreal, int NCT) {
    int tid = blockIdx.x * blockDim.x + threadIdx.x;
    int total = NCT * 8 * 64 * 8;
    if (tid >= total) return;
    int i = tid & 7;
    int lane = (tid >> 3) & 63;
    int q = tid >> 9;
    int c = q % NCT;
    int t = q / NCT;
    int k = t * 32 + (lane >> 4) * 8 + i;
    int n = c * 16 + (lane & 15);
    float v = 0.f;
    if (n < Hreal) v = (k < 128) ? Wl[k * Hreal + n] : Wr[(k - 128) * Hreal + n];
    out[tid] = f2b(v);
}

// ---------------- CSR build: two-level counting sort -------------------------
__global__ void __launch_bounds__(256) hist_k(const int* __restrict__ dst,
                                              unsigned int* __restrict__ cnt,
                                              unsigned int* __restrict__ bhist) {
    __shared__ unsigned int lh[8];
    if (threadIdx.x < 8) lh[threadIdx.x] = 0;
    __syncthreads();
    int start = blockIdx.x * HB_PER;
    for (int i = threadIdx.x; i < HB_PER; i += 256) {
        int d = dst[start + i];
        atomicAdd(&cnt[d], 1u);
        atomicAdd(&lh[(unsigned int)d / BUCKET_N], 1u);
    }
    __syncthreads();
    if (threadIdx.x < 8) bhist[threadIdx.x * HB_BLOCKS + blockIdx.x] = lh[threadIdx.x];
}

__global__ void bscan(unsigned int* __restrict__ A) {
    __shared__ unsigned int part[256];
    int t = threadIdx.x;
    unsigned int v[8];
    unsigned int s = 0;
#pragma unroll
    for (int i = 0; i < 8; i++) { v[i] = A[t * 8 + i]; s += v[i]; }
    part[t] = s; __syncthreads();
    for (int off = 1; off < 256; off <<= 1) {
        unsigned int add = (t >= off) ? part[t - off] : 0u;
        __syncthreads();
        part[t] += add;
        __syncthreads();
    }
    unsigned int base = part[t] - s;  // exclusive
#pragma unroll
    for (int i = 0; i < 8; i++) { unsigned int old = v[i]; A[t * 8 + i] = base; base += old; }
}

__global__ void __launch_bounds__(256) bscatter(const int* __restrict__ src,
                                                const int* __restrict__ dst,
                                                const unsigned int* __restrict__ boffs,
                                                unsigned int* __restrict__ ebuf) {
    __shared__ unsigned int cur[8];
    if (threadIdx.x < 8) cur[threadIdx.x] = boffs[threadIdx.x * HB_BLOCKS + blockIdx.x];
    __syncthreads();
    int start = blockIdx.x * HB_PER;
    for (int i = threadIdx.x; i < HB_PER; i += 256) {
        int d = dst[start + i];
        int s = src[start + i];
        unsigned int b = (unsigned int)d / BUCKET_N;
        unsigned int dl = (unsigned int)d - b * BUCKET_N;
        unsigned int pos = atomicAdd(&cur[b], 1u);
        ebuf[pos] = (unsigned int)s | (dl << 17);
    }
}

__global__ void __launch_bounds__(256) cscatter(const unsigned int* __restrict__ ebuf,
                                                const unsigned int* __restrict__ rowptr,
                                                unsigned int* __restrict__ cursor,
                                                int* __restrict__ srclist) {
    int g = blockIdx.x & 7;
    int gblk = blockIdx.x >> 3;
    unsigned int estart = rowptr[g * BUCKET_N];
    unsigned int eend = (g == 7) ? N_EDGES : rowptr[(g + 1) * BUCKET_N];
    unsigned int nume = eend - estart;
    unsigned int per = (nume + CS_GPB - 1) / CS_GPB;
    unsigned int s0 = estart + gblk * per;
    unsigned int s1 = s0 + per; if (s1 > eend) s1 = eend;
    unsigned int nodebase = g * BUCKET_N;
    for (unsigned int i = s0 + threadIdx.x; i < s1; i += 256) {
        unsigned int p = ebuf[i];
        unsigned int s = p & 0x1FFFFu;
        unsigned int node = nodebase + (p >> 17);
        unsigned int pos = atomicAdd(&cursor[node], 1u);
        srclist[pos] = (int)s;
    }
}

__global__ void scan1(const unsigned int* __restrict__ cnt, unsigned int* __restrict__ rowptr,
                      unsigned int* __restrict__ bsum) {
    __shared__ unsigned int sh[256];
    int t = threadIdx.x;
    int i = blockIdx.x * 256 + t;
    unsigned int v = (i < N_NODES) ? cnt[i] : 0u;
    sh[t] = v; __syncthreads();
    for (int off = 1; off < 256; off <<= 1) {
        unsigned int add = (t >= off) ? sh[t - off] : 0u;
        __syncthreads();
        sh[t] += add;
        __syncthreads();
    }
    if (i < N_NODES) rowptr[i] = sh[t] - v;  // exclusive within block
    if (t == 255) bsum[blockIdx.x] = sh[255];
}

__global__ void scan2(const unsigned int* __restrict__ bsum, unsigned int* __restrict__ boff, int nb) {
    __shared__ unsigned int sh[512];
    int t = threadIdx.x;
    unsigned int v = (t < nb) ? bsum[t] : 0u;
    sh[t] = v; __syncthreads();
    for (int off = 1; off < 512; off <<= 1) {
        unsigned int add = (t >= off) ? sh[t - off] : 0u;
        __syncthreads();
        sh[t] += add;
        __syncthreads();
    }
    if (t < nb) boff[t] = sh[t] - v;
}

__global__ void scan3(unsigned int* __restrict__ rowptr, const unsigned int* __restrict__ boff,
                      unsigned int* __restrict__ cursor) {
    int i = blockIdx.x * 256 + threadIdx.x;
    if (i < N_NODES) {
        unsigned int r = rowptr[i] + boff[blockIdx.x];
        rowptr[i] = r;
        cursor[i] = r;
    }
    if (i == N_NODES) rowptr[N_NODES] = N_EDGES;
}

// ---------------- phase-1: aggregate 16 nodes, 1 node/group ------------------
// R12: R9's divergence-free register-accumulation structure (consecutive node
// assignment -> write/fetch locality intact), with R11's concurrency lever
// kept: unroll-8 first batch = 32 outstanding 16B gathers/wave.
// (R11 post-mortem: degree-permutation raised achieved BW 2.47->3.3 TB/s but
//  doubled traffic via scattered C-writes/root-rows -> net loss. Revert perm,
//  keep unroll-8. If BW falls back to ~2.5, the R11 BW gain was the balance,
//  and the next lever is balancing WITHIN locality windows.)
__device__ __forceinline__ void agg_phase16(const unsigned short* __restrict__ hb,
                                            const unsigned int* __restrict__ rowptr,
                                            const int* __restrict__ srclist,
                                            unsigned int* __restrict__ smean,
                                            int wave, int g, int l, int blockrow) {
    const uint4* hp = (const uint4*)hb;
    int nl = wave * 4 + g;
    int node = blockrow + nl;   // grid is N/16 exactly -> always < N_NODES
    float f0 = 0.f, f1 = 0.f, f2 = 0.f, f3 = 0.f, f4 = 0.f, f5 = 0.f, f6 = 0.f, f7 = 0.f;
    unsigned int b = rowptr[node], e = rowptr[node + 1];
    unsigned int p = b;
#define ACC8(U) { f0 += blo(U.x); f1 += bhi(U.x); f2 += blo(U.y); f3 += bhi(U.y); \
                  f4 += blo(U.z); f5 += bhi(U.z); f6 += blo(U.w); f7 += bhi(U.w); }
    for (; p + 8 <= e; p += 8) {
        int s0 = srclist[p];     int s1 = srclist[p + 1];
        int s2 = srclist[p + 2]; int s3 = srclist[p + 3];
        int s4 = srclist[p + 4]; int s5 = srclist[p + 5];
        int s6 = srclist[p + 6]; int s7 = srclist[p + 7];
        uint4 u0 = hp[(size_t)s0 * 16 + l];
        uint4 u1 = hp[(size_t)s1 * 16 + l];
        uint4 u2 = hp[(size_t)s2 * 16 + l];
        uint4 u3 = hp[(size_t)s3 * 16 + l];
        uint4 u4 = hp[(size_t)s4 * 16 + l];
        uint4 u5 = hp[(size_t)s5 * 16 + l];
        uint4 u6 = hp[(size_t)s6 * 16 + l];
        uint4 u7 = hp[(size_t)s7 * 16 + l];
        ACC8(u0); ACC8(u1); ACC8(u2); ACC8(u3);
        ACC8(u4); ACC8(u5); ACC8(u6); ACC8(u7);
    }
    if (p + 4 <= e) {
        int s0 = srclist[p];     int s1 = srclist[p + 1];
        int s2 = srclist[p + 2]; int s3 = srclist[p + 3];
        uint4 u0 = hp[(size_t)s0 * 16 + l];
        uint4 u1 = hp[(size_t)s1 * 16 + l];
        uint4 u2 = hp[(size_t)s2 * 16 + l];
        uint4 u3 = hp[(size_t)s3 * 16 + l];
        ACC8(u0); ACC8(u1); ACC8(u2); ACC8(u3);
        p += 4;
    }
    if (p + 2 <= e) {
        int s0 = srclist[p];
        int s1 = srclist[p + 1];
        uint4 u0 = hp[(size_t)s0 * 16 + l];
        uint4 u1 = hp[(size_t)s1 * 16 + l];
        ACC8(u0); ACC8(u1);
        p += 2;
    }
    if (p < e) {
        int s0 = srclist[p];
        uint4 u0 = hp[(size_t)s0 * 16 + l];
        ACC8(u0);
    }
#undef ACC8
    unsigned int deg = e - b;
    float r = 1.0f / (float)(deg > 1u ? deg : 1u);
    uint4 o;
    o.x = (unsigned int)f2b(f0 * r) | ((unsigned int)f2b(f1 * r) << 16);
    o.y = (unsigned int)f2b(f2 * r) | ((unsigned int)f2b(f3 * r) << 16);
    o.z = (unsigned int)f2b(f4 * r) | ((unsigned int)f2b(f5 * r) << 16);
    o.w = (unsigned int)f2b(f6 * r) | ((unsigned int)f2b(f7 * r) << 16);
    *(uint4*)&smean[nl * MROW + l * 4] = o;
}

// ---------------- fused agg + GEMM L0/L1 + BN stats + bf16 C -----------------
// 16-row blocks, grid 6250 (= N/16). Phase 2: wave w handles cols [32w,32w+32)
// of all 16 rows (acc = 8 VGPRs). __launch_bounds__(256,8): VGPR <= 64 so the
// unroll-8 in-flight loads can't tip the occupancy cliff.
__global__ void __launch_bounds__(256, 8) gemm2f_k(const unsigned short* __restrict__ hb,
                                                   const unsigned int* __restrict__ rowptr,
                                                   const int* __restrict__ srclist,
                                                   const unsigned short* __restrict__ Bp,
                                                   unsigned short* __restrict__ outb,
                                                   float* __restrict__ sums) {
    __shared__ unsigned int smean[16 * MROW];
    __shared__ float lds_s[128];
    __shared__ float lds_s2[128];
    int wave = threadIdx.x >> 6;
    int lane = threadIdx.x & 63;
    int quad = lane >> 4;
    int l15 = lane & 15;
    int blockrow = blockIdx.x * 16;

    if (threadIdx.x < 128) { lds_s[threadIdx.x] = 0.f; lds_s2[threadIdx.x] = 0.f; }

    agg_phase16(hb, rowptr, srclist, smean, wave, quad, l15, blockrow);
    __syncthreads();

    floatx4 acc[2];
    acc[0] = (floatx4){0.f, 0.f, 0.f, 0.f};
    acc[1] = (floatx4){0.f, 0.f, 0.f, 0.f};

    int r0 = blockrow + l15;   // always < N_NODES (exact division)

#pragma unroll
    for (int t = 0; t < 8; t++) {
        short8 a0;
        if (t < 4) {
            a0 = *(const short8*)&smean[l15 * MROW + t * 16 + quad * 4];
        } else {
            int koff = (t & 3) * 32 + quad * 8;
            a0 = *(const short8*)(hb + (size_t)r0 * 128 + koff);
        }
#pragma unroll
        for (int c = 0; c < 2; c++) {
            int cidx = wave * 2 + c;
            short8 bf = *(const short8*)(Bp + ((size_t)(t * 8 + cidx) * 64 + lane) * 8);
            acc[c] = __builtin_amdgcn_mfma_f32_16x16x32_bf16(a0, bf, acc[c], 0, 0, 0);
        }
    }

#pragma unroll
    for (int c = 0; c < 2; c++) {
        int col = wave * 32 + c * 16 + l15;
        float s = 0.f, s2 = 0.f;
#pragma unroll
        for (int r = 0; r < 4; r++) {
            int row = blockrow + quad * 4 + r;
            float v = acc[c][r];
            outb[(size_t)row * 128 + col] = f2b(v);
            s += v; s2 += v * v;
        }
        s += __shfl_xor(s, 16);  s += __shfl_xor(s, 32);
        s2 += __shfl_xor(s2, 16); s2 += __shfl_xor(s2, 32);
        if (quad == 0) {
            atomicAdd(&lds_s[col], s);
            atomicAdd(&lds_s2[col], s2);
        }
    }

    __syncthreads();
    if (threadIdx.x < 128) {
        int bank = blockIdx.x & (NBANK - 1);
        atomicAdd(&sums[bank * 256 + threadIdx.x], lds_s[threadIdx.x]);
        atomicAdd(&sums[bank * 256 + 128 + threadIdx.x], lds_s2[threadIdx.x]);
    }
}

// ---------------- fused agg + GEMM L2 (40 cols, bias, fp32 out) --------------
// 16-row blocks; waves 0-2 each own one 16-col tile (48 >= 40); wave 3 only
// helps in the gather phase.
__global__ void __launch_bounds__(256, 8) gemm3f_k(const unsigned short* __restrict__ hb,
                                                   const unsigned int* __restrict__ rowptr,
                                                   const int* __restrict__ srclist,
                                                   const unsigned short* __restrict__ Bp,
                                                   const float* __restrict__ bias,
                                                   float* __restrict__ out) {
    __shared__ unsigned int smean[16 * MROW];
    int wave = threadIdx.x >> 6;
    int lane = threadIdx.x & 63;
    int quad = lane >> 4;
    int l15 = lane & 15;
    int blockrow = blockIdx.x * 16;

    agg_phase16(hb, rowptr, srclist, smean, wave, quad, l15, blockrow);
    __syncthreads();

    if (wave >= 3) return;

    floatx4 acc = (floatx4){0.f, 0.f, 0.f, 0.f};
    int r0 = blockrow + l15;

#pragma unroll
    for (int t = 0; t < 8; t++) {
        short8 a0;
        if (t < 4) {
            a0 = *(const short8*)&smean[l15 * MROW + t * 16 + quad * 4];
        } else {
            int koff = (t & 3) * 32 + quad * 8;
            a0 = *(const short8*)(hb + (size_t)r0 * 128 + koff);
        }
        short8 bf = *(const short8*)(Bp + ((size_t)(t * 3 + wave) * 64 + lane) * 8);
        acc = __builtin_amdgcn_mfma_f32_16x16x32_bf16(a0, bf, acc, 0, 0, 0);
    }

    int col = wave * 16 + l15;
    if (col < 40) {
#pragma unroll
        for (int r = 0; r < 4; r++) {
            int row = blockrow + quad * 4 + r;
            out[(size_t)row * 40 + col] = acc[r] + bias[col];
        }
    }
}

// ---------------- BN finalize (reduce 32 banks) ------------------------------
__global__ void bn_finalize(const float* __restrict__ sums, const float* __restrict__ g,
                            const float* __restrict__ be, float* __restrict__ sc,
                            float* __restrict__ sh) {
    __shared__ float lds[256];
    int t = threadIdx.x;
    float s = 0.f;
#pragma unroll 8
    for (int bk = 0; bk < NBANK; bk++) s += sums[bk * 256 + t];
    lds[t] = s;
    __syncthreads();
    if (t < 128) {
        float inv_n = 1.0f / (float)N_NODES;
        float mu = lds[t] * inv_n;
        float var = lds[128 + t] * inv_n - mu * mu;
        float sf = g[t] * rsqrtf(var + EPS);
        sc[t] = sf;
        sh[t] = be[t] - mu * sf;
    }
}

// ---------------- BN apply: bf16 in -> bf16 out, 8 elems/thread --------------
__global__ void bn_apply(const unsigned int* __restrict__ Cb, const float* __restrict__ sc,
                         const float* __restrict__ sh, unsigned short* __restrict__ ho) {
    int i = blockIdx.x * 256 + threadIdx.x;  // one uint4 = 8 bf16
    if (i >= N_NODES * 16) return;
    uint4 v = ((const uint4*)Cb)[i];
    int c0 = (i * 8) & 127;
    uint4 o;
    float e0 = fmaxf(0.f, blo(v.x) * sc[c0 + 0] + sh[c0 + 0]);
    float e1 = fmaxf(0.f, bhi(v.x) * sc[c0 + 1] + sh[c0 + 1]);
    float e2 = fmaxf(0.f, blo(v.y) * sc[c0 + 2] + sh[c0 + 2]);
    float e3 = fmaxf(0.f, bhi(v.y) * sc[c0 + 3] + sh[c0 + 3]);
    float e4 = fmaxf(0.f, blo(v.z) * sc[c0 + 4] + sh[c0 + 4]);
    float e5 = fmaxf(0.f, bhi(v.z) * sc[c0 + 5] + sh[c0 + 5]);
    float e6 = fmaxf(0.f, blo(v.w) * sc[c0 + 6] + sh[c0 + 6]);
    float e7 = fmaxf(0.f, bhi(v.w) * sc[c0 + 7] + sh[c0 + 7]);
    o.x = (unsigned int)f2b(e0) | ((unsigned int)f2b(e1) << 16);
    o.y = (unsigned int)f2b(e2) | ((unsigned int)f2b(e3) << 16);
    o.z = (unsigned int)f2b(e4) | ((unsigned int)f2b(e5) << 16);
    o.w = (unsigned int)f2b(e6) | ((unsigned int)f2b(e7) << 16);
    ((uint4*)ho)[i] = o;
}

// ---------------- host ----------------
extern "C" void kernel_launch(void* const* d_in, const int* in_sizes, int n_in,
                              void* d_out, int out_size, void* d_ws, size_t ws_size,
                              hipStream_t stream) {
    const float* x   = (const float*)d_in[0];
    const int* ei    = (const int*)d_in[1];     // [2, E] int32: row 0 = src, row 1 = dst
    const float* Wl0 = (const float*)d_in[2];
    const float* Wr0 = (const float*)d_in[3];
    const float* Wl1 = (const float*)d_in[4];
    const float* Wr1 = (const float*)d_in[5];
    const float* Wl2 = (const float*)d_in[6];
    const float* Wr2 = (const float*)d_in[7];
    const float* b2  = (const float*)d_in[8];
    const float* g0  = (const float*)d_in[9];
    const float* be0 = (const float*)d_in[10];
    const float* g1  = (const float*)d_in[11];
    const float* be1 = (const float*)d_in[12];

    char* ws = (char*)d_ws;
    size_t off = 0;
    auto alloc = [&](size_t bytes) -> void* {
        void* p = ws + off;
        off += (bytes + 4095) & ~(size_t)4095;
        return p;
    };

    const size_t NB16 = (size_t)N_NODES * 128 * 2;  // 25.6 MB bf16 feature buffer
    unsigned short* xb   = (unsigned short*)alloc(NB16);   // x in bf16; reused as h2
    unsigned short* h1   = (unsigned short*)alloc(NB16);
    unsigned short* C    = (unsigned short*)alloc(NB16);   // pre-BN bf16
    unsigned int* cnt    = (unsigned int*)alloc((size_t)N_NODES * 4);
    unsigned int* rowptr = (unsigned int*)alloc((size_t)(N_NODES + 1) * 4);
    unsigned int* cursor = (unsigned int*)alloc((size_t)N_NODES * 4);
    int* srclist         = (int*)alloc((size_t)N_EDGES * 4);
    unsigned int* ebuf   = (unsigned int*)alloc((size_t)N_EDGES * 4);
    unsigned int* bhist  = (unsigned int*)alloc(8 * HB_BLOCKS * 4);
    unsigned int* bsum   = (unsigned int*)alloc(512 * 4);
    unsigned int* boff   = (unsigned int*)alloc(512 * 4);
    float* sums0         = (float*)alloc(NBANK * 256 * 4);   // contiguous with sums1
    float* sums1         = (float*)alloc(NBANK * 256 * 4);
    float* sc            = (float*)alloc(128 * 4);
    float* sh            = (float*)alloc(128 * 4);
    unsigned short* W0p  = (unsigned short*)alloc(8 * 8 * 64 * 8 * 2);
    unsigned short* W1p  = (unsigned short*)alloc(8 * 8 * 64 * 8 * 2);
    unsigned short* W2p  = (unsigned short*)alloc(3 * 8 * 64 * 8 * 2);
    unsigned short* h2   = xb;  // alias: xb dead after layer-0 GEMM

    const int* srcp = ei;
    const int* dstp = ei + N_EDGES;

    // ---- prep (both BN sums buffers zeroed up front; none mid-pipeline) ----
    hipMemsetAsync(cnt, 0, (size_t)N_NODES * 4, stream);
    hipMemsetAsync(sums0, 0, (size_t)2 * NBANK * 256 * 4, stream);  // sums0+sums1
    cvt_f32_bf16<<<12500, 256, 0, stream>>>(x, xb, N_NODES * 32);
    pack_w<<<(8 * 4096 + 255) / 256, 256, 0, stream>>>(Wl0, Wr0, W0p, 128, 8);
    pack_w<<<(8 * 4096 + 255) / 256, 256, 0, stream>>>(Wl1, Wr1, W1p, 128, 8);
    pack_w<<<(3 * 4096 + 255) / 256, 256, 0, stream>>>(Wl2, Wr2, W2p, 40, 3);

    // ---- CSR (two-level counting sort) ----
    hist_k<<<HB_BLOCKS, 256, 0, stream>>>(dstp, cnt, bhist);
    scan1<<<391, 256, 0, stream>>>(cnt, rowptr, bsum);
    scan2<<<1, 512, 0, stream>>>(bsum, boff, 391);
    scan3<<<391, 256, 0, stream>>>(rowptr, boff, cursor);
    bscan<<<1, 256, 0, stream>>>(bhist);
    bscatter<<<HB_BLOCKS, 256, 0, stream>>>(srcp, dstp, bhist, ebuf);
    cscatter<<<8 * CS_GPB, 256, 0, stream>>>(ebuf, rowptr, cursor, srclist);

    // ---- layer 0 (fused agg+gemm, 16-row blocks) ----
    gemm2f_k<<<6250, 256, 0, stream>>>(xb, rowptr, srclist, W0p, C, sums0);
    bn_finalize<<<1, 256, 0, stream>>>(sums0, g0, be0, sc, sh);
    bn_apply<<<6250, 256, 0, stream>>>((const unsigned int*)C, sc, sh, h1);

    // ---- layer 1 ----
    gemm2f_k<<<6250, 256, 0, stream>>>(h1, rowptr, srclist, W1p, C, sums1);
    bn_finalize<<<1, 256, 0, stream>>>(sums1, g1, be1, sc, sh);
    bn_apply<<<6250, 256, 0, stream>>>((const unsigned int*)C, sc, sh, h2);

    // ---- layer 2 (writes d_out, fp32 [N,40]) ----
    gemm3f_k<<<6250, 256, 0, stream>>>(h2, rowptr, srclist, W2p, b2, (float*)d_out);

    (void)in_sizes; (void)n_in; (void)out_size; (void)ws_size;
}

// Round 4
// 360.568 us; speedup vs baseline: 1.7909x; 1.2239x over previous
//
#include <hip/hip_runtime.h>
#include <hip/hip_bf16.h>

#define N_NODES 100000
#define N_EDGES 800000
#define EPS 1e-5f
#define NBANK 32
#define HB_BLOCKS 256
#define HB_PER 3125          // 256 * 3125 = 800000 exactly
#define CS_GPB 64            // cscatter blocks per coarse bucket
#define BUCKET_N 12500       // 8 * 12500 = 100000 exactly
#define MROW 68              // LDS mean row stride in dwords (64 + 4 pad)

typedef __attribute__((ext_vector_type(8))) short short8;
typedef __attribute__((ext_vector_type(4))) float floatx4;

__device__ __forceinline__ unsigned short f2b(float f) {
    unsigned int u = __float_as_uint(f);
    u = (u + 0x7fffu + ((u >> 16) & 1u)) >> 16;   // round-to-nearest-even
    return (unsigned short)u;
}
__device__ __forceinline__ float blo(unsigned int u) { return __uint_as_float(u << 16); }
__device__ __forceinline__ float bhi(unsigned int u) { return __uint_as_float(u & 0xffff0000u); }
__device__ __forceinline__ float b2f(unsigned short s) {
    return __uint_as_float(((unsigned int)s) << 16);
}

// ---------------- elementwise convert fp32 -> bf16 (x input) ----------------
__global__ void cvt_f32_bf16(const float* __restrict__ x, unsigned short* __restrict__ o, int n4) {
    int i = blockIdx.x * blockDim.x + threadIdx.x;
    if (i >= n4) return;
    float4 v = ((const float4*)x)[i];
    ushort4 r;
    r.x = f2b(v.x); r.y = f2b(v.y); r.z = f2b(v.z); r.w = f2b(v.w);
    ((ushort4*)o)[i] = r;
}

// ---------------- pack [Wl;Wr] (K=256 x Hreal) into MFMA B-fragment order ----
__global__ void pack_w(const float* __restrict__ Wl, const float* __restrict__ Wr,
                       unsigned short* __restrict__ out, int Hreal, int NCT) {
    int tid = blockIdx.x * blockDim.x + threadIdx.x;
    int total = NCT * 8 * 64 * 8;
    if (tid >= total) return;
    int i = tid & 7;
    int lane = (tid >> 3) & 63;
    int q = tid >> 9;
    int c = q % NCT;
    int t = q / NCT;
    int k = t * 32 + (lane >> 4) * 8 + i;
    int n = c * 16 + (lane & 15);
    float v = 0.f;
    if (n < Hreal) v = (k < 128) ? Wl[k * Hreal + n] : Wr[(k - 128) * Hreal + n];
    out[tid] = f2b(v);
}

// ---------------- CSR build: two-level counting sort -------------------------
__global__ void __launch_bounds__(256) hist_k(const int* __restrict__ dst,
                                              unsigned int* __restrict__ cnt,
                                              unsigned int* __restrict__ bhist) {
    __shared__ unsigned int lh[8];
    if (threadIdx.x < 8) lh[threadIdx.x] = 0;
    __syncthreads();
    int start = blockIdx.x * HB_PER;
    for (int i = threadIdx.x; i < HB_PER; i += 256) {
        int d = dst[start + i];
        atomicAdd(&cnt[d], 1u);
        atomicAdd(&lh[(unsigned int)d / BUCKET_N], 1u);
    }
    __syncthreads();
    if (threadIdx.x < 8) bhist[threadIdx.x * HB_BLOCKS + blockIdx.x] = lh[threadIdx.x];
}

__global__ void bscan(unsigned int* __restrict__ A) {
    __shared__ unsigned int part[256];
    int t = threadIdx.x;
    unsigned int v[8];
    unsigned int s = 0;
#pragma unroll
    for (int i = 0; i < 8; i++) { v[i] = A[t * 8 + i]; s += v[i]; }
    part[t] = s; __syncthreads();
    for (int off = 1; off < 256; off <<= 1) {
        unsigned int add = (t >= off) ? part[t - off] : 0u;
        __syncthreads();
        part[t] += add;
        __syncthreads();
    }
    unsigned int base = part[t] - s;  // exclusive
#pragma unroll
    for (int i = 0; i < 8; i++) { unsigned int old = v[i]; A[t * 8 + i] = base; base += old; }
}

__global__ void __launch_bounds__(256) bscatter(const int* __restrict__ src,
                                                const int* __restrict__ dst,
                                                const unsigned int* __restrict__ boffs,
                                                unsigned int* __restrict__ ebuf) {
    __shared__ unsigned int cur[8];
    if (threadIdx.x < 8) cur[threadIdx.x] = boffs[threadIdx.x * HB_BLOCKS + blockIdx.x];
    __syncthreads();
    int start = blockIdx.x * HB_PER;
    for (int i = threadIdx.x; i < HB_PER; i += 256) {
        int d = dst[start + i];
        int s = src[start + i];
        unsigned int b = (unsigned int)d / BUCKET_N;
        unsigned int dl = (unsigned int)d - b * BUCKET_N;
        unsigned int pos = atomicAdd(&cur[b], 1u);
        ebuf[pos] = (unsigned int)s | (dl << 17);
    }
}

__global__ void __launch_bounds__(256) cscatter(const unsigned int* __restrict__ ebuf,
                                                const unsigned int* __restrict__ rowptr,
                                                unsigned int* __restrict__ cursor,
                                                int* __restrict__ srclist) {
    int g = blockIdx.x & 7;
    int gblk = blockIdx.x >> 3;
    unsigned int estart = rowptr[g * BUCKET_N];
    unsigned int eend = (g == 7) ? N_EDGES : rowptr[(g + 1) * BUCKET_N];
    unsigned int nume = eend - estart;
    unsigned int per = (nume + CS_GPB - 1) / CS_GPB;
    unsigned int s0 = estart + gblk * per;
    unsigned int s1 = s0 + per; if (s1 > eend) s1 = eend;
    unsigned int nodebase = g * BUCKET_N;
    for (unsigned int i = s0 + threadIdx.x; i < s1; i += 256) {
        unsigned int p = ebuf[i];
        unsigned int s = p & 0x1FFFFu;
        unsigned int node = nodebase + (p >> 17);
        unsigned int pos = atomicAdd(&cursor[node], 1u);
        srclist[pos] = (int)s;
    }
}

__global__ void scan1(const unsigned int* __restrict__ cnt, unsigned int* __restrict__ rowptr,
                      unsigned int* __restrict__ bsum) {
    __shared__ unsigned int sh[256];
    int t = threadIdx.x;
    int i = blockIdx.x * 256 + t;
    unsigned int v = (i < N_NODES) ? cnt[i] : 0u;
    sh[t] = v; __syncthreads();
    for (int off = 1; off < 256; off <<= 1) {
        unsigned int add = (t >= off) ? sh[t - off] : 0u;
        __syncthreads();
        sh[t] += add;
        __syncthreads();
    }
    if (i < N_NODES) rowptr[i] = sh[t] - v;  // exclusive within block
    if (t == 255) bsum[blockIdx.x] = sh[255];
}

__global__ void scan2(const unsigned int* __restrict__ bsum, unsigned int* __restrict__ boff, int nb) {
    __shared__ unsigned int sh[512];
    int t = threadIdx.x;
    unsigned int v = (t < nb) ? bsum[t] : 0u;
    sh[t] = v; __syncthreads();
    for (int off = 1; off < 512; off <<= 1) {
        unsigned int add = (t >= off) ? sh[t - off] : 0u;
        __syncthreads();
        sh[t] += add;
        __syncthreads();
    }
    if (t < nb) boff[t] = sh[t] - v;
}

__global__ void scan3(unsigned int* __restrict__ rowptr, const unsigned int* __restrict__ boff,
                      unsigned int* __restrict__ cursor) {
    int i = blockIdx.x * 256 + threadIdx.x;
    if (i < N_NODES) {
        unsigned int r = rowptr[i] + boff[blockIdx.x];
        rowptr[i] = r;
        cursor[i] = r;
    }
    if (i == N_NODES) rowptr[N_NODES] = N_EDGES;
}

// ---------------- phase-1: aggregate 16 nodes, 1 node/group ------------------
// R13: exact R9 structure (unroll-4, consecutive nodes, no launch-bounds cap).
// R12 post-mortem: unroll-8 inflated past-L2 traffic (158/100 MB vs 101/31) --
// deeper queues thrash L2 (early dirty-line eviction + lost feature-row reuse).
// The gather sits at a ~2.5-3 TB/s random-256B ceiling; lever = FEWER BYTES.
// BN template param: gather the PRE-BN C buffer and apply relu(c*sc+sh) inline
// (sc/sh preloaded to 16 regs) -> bn_apply kernels and h-buffer deleted.
template<int BN>
__device__ __forceinline__ void agg_phase16(const unsigned short* __restrict__ hb,
                                            const unsigned int* __restrict__ rowptr,
                                            const int* __restrict__ srclist,
                                            unsigned int* __restrict__ smean,
                                            const float* __restrict__ sc,
                                            const float* __restrict__ sh,
                                            int wave, int g, int l, int blockrow) {
    const uint4* hp = (const uint4*)hb;
    int nl = wave * 4 + g;
    int node = blockrow + nl;   // grid is N/16 exactly -> always < N_NODES
    float f0 = 0.f, f1 = 0.f, f2 = 0.f, f3 = 0.f, f4 = 0.f, f5 = 0.f, f6 = 0.f, f7 = 0.f;
    float sc0r = 0.f, sc1r = 0.f, sc2r = 0.f, sc3r = 0.f, sc4r = 0.f, sc5r = 0.f, sc6r = 0.f, sc7r = 0.f;
    float sh0r = 0.f, sh1r = 0.f, sh2r = 0.f, sh3r = 0.f, sh4r = 0.f, sh5r = 0.f, sh6r = 0.f, sh7r = 0.f;
    if (BN) {
        const float* s0 = sc + l * 8;
        const float* s1 = sh + l * 8;
        sc0r = s0[0]; sc1r = s0[1]; sc2r = s0[2]; sc3r = s0[3];
        sc4r = s0[4]; sc5r = s0[5]; sc6r = s0[6]; sc7r = s0[7];
        sh0r = s1[0]; sh1r = s1[1]; sh2r = s1[2]; sh3r = s1[3];
        sh4r = s1[4]; sh5r = s1[5]; sh6r = s1[6]; sh7r = s1[7];
    }
    unsigned int b = rowptr[node], e = rowptr[node + 1];
    unsigned int p = b;
#define ACC8(U) { \
    if (BN) { \
        f0 += fmaxf(0.f, fmaf(blo(U.x), sc0r, sh0r)); \
        f1 += fmaxf(0.f, fmaf(bhi(U.x), sc1r, sh1r)); \
        f2 += fmaxf(0.f, fmaf(blo(U.y), sc2r, sh2r)); \
        f3 += fmaxf(0.f, fmaf(bhi(U.y), sc3r, sh3r)); \
        f4 += fmaxf(0.f, fmaf(blo(U.z), sc4r, sh4r)); \
        f5 += fmaxf(0.f, fmaf(bhi(U.z), sc5r, sh5r)); \
        f6 += fmaxf(0.f, fmaf(blo(U.w), sc6r, sh6r)); \
        f7 += fmaxf(0.f, fmaf(bhi(U.w), sc7r, sh7r)); \
    } else { \
        f0 += blo(U.x); f1 += bhi(U.x); f2 += blo(U.y); f3 += bhi(U.y); \
        f4 += blo(U.z); f5 += bhi(U.z); f6 += blo(U.w); f7 += bhi(U.w); \
    } }
    for (; p + 4 <= e; p += 4) {
        int s0 = srclist[p];
        int s1 = srclist[p + 1];
        int s2 = srclist[p + 2];
        int s3 = srclist[p + 3];
        uint4 u0 = hp[(size_t)s0 * 16 + l];
        uint4 u1 = hp[(size_t)s1 * 16 + l];
        uint4 u2 = hp[(size_t)s2 * 16 + l];
        uint4 u3 = hp[(size_t)s3 * 16 + l];
        ACC8(u0); ACC8(u1); ACC8(u2); ACC8(u3);
    }
    if (p + 2 <= e) {
        int s0 = srclist[p];
        int s1 = srclist[p + 1];
        uint4 u0 = hp[(size_t)s0 * 16 + l];
        uint4 u1 = hp[(size_t)s1 * 16 + l];
        ACC8(u0); ACC8(u1);
        p += 2;
    }
    if (p < e) {
        int s0 = srclist[p];
        uint4 u0 = hp[(size_t)s0 * 16 + l];
        ACC8(u0);
    }
#undef ACC8
    unsigned int deg = e - b;
    float r = 1.0f / (float)(deg > 1u ? deg : 1u);
    uint4 o;
    o.x = (unsigned int)f2b(f0 * r) | ((unsigned int)f2b(f1 * r) << 16);
    o.y = (unsigned int)f2b(f2 * r) | ((unsigned int)f2b(f3 * r) << 16);
    o.z = (unsigned int)f2b(f4 * r) | ((unsigned int)f2b(f5 * r) << 16);
    o.w = (unsigned int)f2b(f6 * r) | ((unsigned int)f2b(f7 * r) << 16);
    *(uint4*)&smean[nl * MROW + l * 4] = o;
}

// bn+relu+repack an 8-element bf16 fragment using LDS-staged sc/sh (root rows)
__device__ __forceinline__ short8 bn_pack8(short8 raw, const float* __restrict__ scb,
                                           const float* __restrict__ shb, int koff) {
    short8 r;
#pragma unroll
    for (int i = 0; i < 8; i++) {
        float v = b2f((unsigned short)raw[i]);
        v = fmaxf(0.f, fmaf(v, scb[koff + i], shb[koff + i]));
        r[i] = (short)f2b(v);
    }
    return r;
}

// ---------------- fused agg + GEMM L0/L1 + BN stats + bf16 C -----------------
// 16-row blocks, grid 6250 (= N/16). Phase 2: wave w handles cols [32w,32w+32)
// of all 16 rows (acc = 8 VGPRs). BN=1: input is pre-BN C of previous layer;
// relu(bn()) applied inline in gather and root-row loads.
template<int BN>
__global__ void __launch_bounds__(256) gemm2f_k(const unsigned short* __restrict__ hb,
                                                const unsigned int* __restrict__ rowptr,
                                                const int* __restrict__ srclist,
                                                const float* __restrict__ sc,
                                                const float* __restrict__ sh,
                                                const unsigned short* __restrict__ Bp,
                                                unsigned short* __restrict__ outb,
                                                float* __restrict__ sums) {
    __shared__ unsigned int smean[16 * MROW];
    __shared__ float lds_s[128];
    __shared__ float lds_s2[128];
    __shared__ float scb[128];
    __shared__ float shb[128];
    int wave = threadIdx.x >> 6;
    int lane = threadIdx.x & 63;
    int quad = lane >> 4;
    int l15 = lane & 15;
    int blockrow = blockIdx.x * 16;

    if (threadIdx.x < 128) {
        lds_s[threadIdx.x] = 0.f; lds_s2[threadIdx.x] = 0.f;
        if (BN) { scb[threadIdx.x] = sc[threadIdx.x]; shb[threadIdx.x] = sh[threadIdx.x]; }
    }
    if (BN) __syncthreads();   // scb/shb visible to phase 2 root loads

    agg_phase16<BN>(hb, rowptr, srclist, smean, sc, sh, wave, quad, l15, blockrow);
    __syncthreads();

    floatx4 acc[2];
    acc[0] = (floatx4){0.f, 0.f, 0.f, 0.f};
    acc[1] = (floatx4){0.f, 0.f, 0.f, 0.f};

    int r0 = blockrow + l15;   // always < N_NODES (exact division)

#pragma unroll
    for (int t = 0; t < 8; t++) {
        short8 a0;
        if (t < 4) {
            a0 = *(const short8*)&smean[l15 * MROW + t * 16 + quad * 4];
        } else {
            int koff = (t & 3) * 32 + quad * 8;
            short8 raw = *(const short8*)(hb + (size_t)r0 * 128 + koff);
            a0 = BN ? bn_pack8(raw, scb, shb, koff) : raw;
        }
#pragma unroll
        for (int c = 0; c < 2; c++) {
            int cidx = wave * 2 + c;
            short8 bf = *(const short8*)(Bp + ((size_t)(t * 8 + cidx) * 64 + lane) * 8);
            acc[c] = __builtin_amdgcn_mfma_f32_16x16x32_bf16(a0, bf, acc[c], 0, 0, 0);
        }
    }

#pragma unroll
    for (int c = 0; c < 2; c++) {
        int col = wave * 32 + c * 16 + l15;
        float s = 0.f, s2 = 0.f;
#pragma unroll
        for (int r = 0; r < 4; r++) {
            int row = blockrow + quad * 4 + r;
            float v = acc[c][r];
            outb[(size_t)row * 128 + col] = f2b(v);
            s += v; s2 += v * v;
        }
        s += __shfl_xor(s, 16);  s += __shfl_xor(s, 32);
        s2 += __shfl_xor(s2, 16); s2 += __shfl_xor(s2, 32);
        if (quad == 0) {
            atomicAdd(&lds_s[col], s);
            atomicAdd(&lds_s2[col], s2);
        }
    }

    __syncthreads();
    if (threadIdx.x < 128) {
        int bank = blockIdx.x & (NBANK - 1);
        atomicAdd(&sums[bank * 256 + threadIdx.x], lds_s[threadIdx.x]);
        atomicAdd(&sums[bank * 256 + 128 + threadIdx.x], lds_s2[threadIdx.x]);
    }
}

// ---------------- layer-2 dense: P = h2@Wl2 (bf16, 64-col pad), Q = h2@Wr2+b2 -
// mean is linear: out = mean(P[src]) + Q. Transform-first shrinks the layer-2
// gather from 256B to 128B rows. h2 = relu(bn1(C1)) applied inline.
__global__ void __launch_bounds__(256) dense_k(const unsigned short* __restrict__ hb,
                                               const float* __restrict__ sc,
                                               const float* __restrict__ sh,
                                               const unsigned short* __restrict__ Bp,
                                               const float* __restrict__ bias,
                                               unsigned short* __restrict__ P,
                                               float* __restrict__ Q) {
    __shared__ float scb[128];
    __shared__ float shb[128];
    int wave = threadIdx.x >> 6;
    int lane = threadIdx.x & 63;
    int quad = lane >> 4;
    int l15 = lane & 15;
    int blockrow = blockIdx.x * 16;

    if (threadIdx.x < 128) { scb[threadIdx.x] = sc[threadIdx.x]; shb[threadIdx.x] = sh[threadIdx.x]; }
    __syncthreads();

    int r0 = blockrow + l15;
    short8 af[4];
#pragma unroll
    for (int t = 0; t < 4; t++) {
        int koff = t * 32 + quad * 8;
        short8 raw = *(const short8*)(hb + (size_t)r0 * 128 + koff);
        af[t] = bn_pack8(raw, scb, shb, koff);
    }

    if (wave < 3) {
        floatx4 aP = (floatx4){0.f, 0.f, 0.f, 0.f};
        floatx4 aQ = (floatx4){0.f, 0.f, 0.f, 0.f};
#pragma unroll
        for (int t = 0; t < 4; t++) {
            short8 bl = *(const short8*)(Bp + ((size_t)(t * 3 + wave) * 64 + lane) * 8);
            aP = __builtin_amdgcn_mfma_f32_16x16x32_bf16(af[t], bl, aP, 0, 0, 0);
        }
#pragma unroll
        for (int t = 0; t < 4; t++) {
            short8 br = *(const short8*)(Bp + ((size_t)((t + 4) * 3 + wave) * 64 + lane) * 8);
            aQ = __builtin_amdgcn_mfma_f32_16x16x32_bf16(af[t], br, aQ, 0, 0, 0);
        }
        int col = wave * 16 + l15;
#pragma unroll
        for (int r = 0; r < 4; r++) {
            int row = blockrow + quad * 4 + r;
            P[(size_t)row * 64 + col] = f2b(aP[r]);     // cols 40..47 are zero (padded W)
        }
        if (col < 40) {
#pragma unroll
            for (int r = 0; r < 4; r++) {
                int row = blockrow + quad * 4 + r;
                Q[(size_t)row * 40 + col] = aQ[r] + bias[col];
            }
        }
    } else {
        // wave 3: zero-fill pad cols 48..63 so agg40's discard lanes read clean data
#pragma unroll
        for (int r = 0; r < 4; r++) {
            int row = blockrow + quad * 4 + r;
            P[(size_t)row * 64 + 48 + l15] = 0;
        }
    }
}

// ---------------- layer-2 aggregate: out = mean(P[src]) + Q ------------------
// 8-lane groups, 32 nodes/block, grid 3125 (= N/32). 128B rows (uint4/lane).
__global__ void __launch_bounds__(256) agg40_k(const unsigned short* __restrict__ P,
                                               const unsigned int* __restrict__ rowptr,
                                               const int* __restrict__ srclist,
                                               const float* __restrict__ Q,
                                               float* __restrict__ out) {
    int tid = threadIdx.x;
    int g = tid >> 3;        // group 0..31
    int l = tid & 7;         // lane in group
    int node = blockIdx.x * 32 + g;   // 3125*32 = 100000 exactly
    const uint4* pp = (const uint4*)P;
    float f0 = 0.f, f1 = 0.f, f2 = 0.f, f3 = 0.f, f4 = 0.f, f5 = 0.f, f6 = 0.f, f7 = 0.f;
    unsigned int b = rowptr[node], e = rowptr[node + 1];
    unsigned int p = b;
#define ACC8(U) { f0 += blo(U.x); f1 += bhi(U.x); f2 += blo(U.y); f3 += bhi(U.y); \
                  f4 += blo(U.z); f5 += bhi(U.z); f6 += blo(U.w); f7 += bhi(U.w); }
    for (; p + 4 <= e; p += 4) {
        int s0 = srclist[p];
        int s1 = srclist[p + 1];
        int s2 = srclist[p + 2];
        int s3 = srclist[p + 3];
        uint4 u0 = pp[(size_t)s0 * 8 + l];
        uint4 u1 = pp[(size_t)s1 * 8 + l];
        uint4 u2 = pp[(size_t)s2 * 8 + l];
        uint4 u3 = pp[(size_t)s3 * 8 + l];
        ACC8(u0); ACC8(u1); ACC8(u2); ACC8(u3);
    }
    if (p + 2 <= e) {
        int s0 = srclist[p];
        int s1 = srclist[p + 1];
        uint4 u0 = pp[(size_t)s0 * 8 + l];
        uint4 u1 = pp[(size_t)s1 * 8 + l];
        ACC8(u0); ACC8(u1);
        p += 2;
    }
    if (p < e) {
        int s0 = srclist[p];
        uint4 u0 = pp[(size_t)s0 * 8 + l];
        ACC8(u0);
    }
#undef ACC8
    unsigned int deg = e - b;
    float r = 1.0f / (float)(deg > 1u ? deg : 1u);
    if (l < 5) {   // cols l*8 .. l*8+8 of 40
        size_t base = (size_t)node * 40 + l * 8;
        float4 o1, o2;
        o1.x = f0 * r + Q[base + 0]; o1.y = f1 * r + Q[base + 1];
        o1.z = f2 * r + Q[base + 2]; o1.w = f3 * r + Q[base + 3];
        o2.x = f4 * r + Q[base + 4]; o2.y = f5 * r + Q[base + 5];
        o2.z = f6 * r + Q[base + 6]; o2.w = f7 * r + Q[base + 7];
        *(float4*)(out + base) = o1;
        *(float4*)(out + base + 4) = o2;
    }
}

// ---------------- BN finalize (reduce 32 banks) ------------------------------
__global__ void bn_finalize(const float* __restrict__ sums, const float* __restrict__ g,
                            const float* __restrict__ be, float* __restrict__ sc,
                            float* __restrict__ sh) {
    __shared__ float lds[256];
    int t = threadIdx.x;
    float s = 0.f;
#pragma unroll 8
    for (int bk = 0; bk < NBANK; bk++) s += sums[bk * 256 + t];
    lds[t] = s;
    __syncthreads();
    if (t < 128) {
        float inv_n = 1.0f / (float)N_NODES;
        float mu = lds[t] * inv_n;
        float var = lds[128 + t] * inv_n - mu * mu;
        float sf = g[t] * rsqrtf(var + EPS);
        sc[t] = sf;
        sh[t] = be[t] - mu * sf;
    }
}

// ---------------- host ----------------
extern "C" void kernel_launch(void* const* d_in, const int* in_sizes, int n_in,
                              void* d_out, int out_size, void* d_ws, size_t ws_size,
                              hipStream_t stream) {
    const float* x   = (const float*)d_in[0];
    const int* ei    = (const int*)d_in[1];     // [2, E] int32: row 0 = src, row 1 = dst
    const float* Wl0 = (const float*)d_in[2];
    const float* Wr0 = (const float*)d_in[3];
    const float* Wl1 = (const float*)d_in[4];
    const float* Wr1 = (const float*)d_in[5];
    const float* Wl2 = (const float*)d_in[6];
    const float* Wr2 = (const float*)d_in[7];
    const float* b2  = (const float*)d_in[8];
    const float* g0  = (const float*)d_in[9];
    const float* be0 = (const float*)d_in[10];
    const float* g1  = (const float*)d_in[11];
    const float* be1 = (const float*)d_in[12];

    char* ws = (char*)d_ws;
    size_t off = 0;
    auto alloc = [&](size_t bytes) -> void* {
        void* p = ws + off;
        off += (bytes + 4095) & ~(size_t)4095;
        return p;
    };

    const size_t NB16 = (size_t)N_NODES * 128 * 2;  // 25.6 MB bf16 feature buffer
    unsigned short* xb   = (unsigned short*)alloc(NB16);   // x bf16; reused as Q (fp32 16MB)
    unsigned short* C0b  = (unsigned short*)alloc(NB16);   // layer-0 pre-BN C; reused as P64
    unsigned short* C1b  = (unsigned short*)alloc(NB16);   // layer-1 pre-BN C
    unsigned int* cnt    = (unsigned int*)alloc((size_t)N_NODES * 4);
    unsigned int* rowptr = (unsigned int*)alloc((size_t)(N_NODES + 1) * 4);
    unsigned int* cursor = (unsigned int*)alloc((size_t)N_NODES * 4);
    int* srclist         = (int*)alloc((size_t)N_EDGES * 4);
    unsigned int* ebuf   = (unsigned int*)alloc((size_t)N_EDGES * 4);
    unsigned int* bhist  = (unsigned int*)alloc(8 * HB_BLOCKS * 4);
    unsigned int* bsum   = (unsigned int*)alloc(512 * 4);
    unsigned int* boff   = (unsigned int*)alloc(512 * 4);
    float* sums0         = (float*)alloc(NBANK * 256 * 4);   // contiguous with sums1
    float* sums1         = (float*)alloc(NBANK * 256 * 4);
    float* sc            = (float*)alloc(128 * 4);
    float* sh            = (float*)alloc(128 * 4);
    unsigned short* W0p  = (unsigned short*)alloc(8 * 8 * 64 * 8 * 2);
    unsigned short* W1p  = (unsigned short*)alloc(8 * 8 * 64 * 8 * 2);
    unsigned short* W2p  = (unsigned short*)alloc(3 * 8 * 64 * 8 * 2);

    unsigned short* P64  = C0b;           // 12.8 MB, C0 dead after layer-1 gemm
    float* Q             = (float*)xb;    // 16 MB, xb dead after layer-0 gemm

    const int* srcp = ei;
    const int* dstp = ei + N_EDGES;

    // ---- prep (both BN sums buffers zeroed up front; none mid-pipeline) ----
    hipMemsetAsync(cnt, 0, (size_t)N_NODES * 4, stream);
    hipMemsetAsync(sums0, 0, (size_t)2 * NBANK * 256 * 4, stream);  // sums0+sums1
    cvt_f32_bf16<<<12500, 256, 0, stream>>>(x, xb, N_NODES * 32);
    pack_w<<<(8 * 4096 + 255) / 256, 256, 0, stream>>>(Wl0, Wr0, W0p, 128, 8);
    pack_w<<<(8 * 4096 + 255) / 256, 256, 0, stream>>>(Wl1, Wr1, W1p, 128, 8);
    pack_w<<<(3 * 4096 + 255) / 256, 256, 0, stream>>>(Wl2, Wr2, W2p, 40, 3);

    // ---- CSR (two-level counting sort) ----
    hist_k<<<HB_BLOCKS, 256, 0, stream>>>(dstp, cnt, bhist);
    scan1<<<391, 256, 0, stream>>>(cnt, rowptr, bsum);
    scan2<<<1, 512, 0, stream>>>(bsum, boff, 391);
    scan3<<<391, 256, 0, stream>>>(rowptr, boff, cursor);
    bscan<<<1, 256, 0, stream>>>(bhist);
    bscatter<<<HB_BLOCKS, 256, 0, stream>>>(srcp, dstp, bhist, ebuf);
    cscatter<<<8 * CS_GPB, 256, 0, stream>>>(ebuf, rowptr, cursor, srclist);

    // ---- layer 0: agg+gemm from x (no input BN) -> C0, stats0 ----
    gemm2f_k<0><<<6250, 256, 0, stream>>>(xb, rowptr, srclist, nullptr, nullptr, W0p, C0b, sums0);
    bn_finalize<<<1, 256, 0, stream>>>(sums0, g0, be0, sc, sh);

    // ---- layer 1: agg+gemm from C0 with inline relu(bn0) -> C1, stats1 ----
    gemm2f_k<1><<<6250, 256, 0, stream>>>(C0b, rowptr, srclist, sc, sh, W1p, C1b, sums1);
    bn_finalize<<<1, 256, 0, stream>>>(sums1, g1, be1, sc, sh);

    // ---- layer 2: transform-first (mean is linear) ----
    dense_k<<<6250, 256, 0, stream>>>(C1b, sc, sh, W2p, b2, P64, Q);
    agg40_k<<<3125, 256, 0, stream>>>(P64, rowptr, srclist, Q, (float*)d_out);

    (void)in_sizes; (void)n_in; (void)out_size; (void)ws_size;
}

// Round 5
// 360.182 us; speedup vs baseline: 1.7928x; 1.0011x over previous
//
#include <hip/hip_runtime.h>
#include <hip/hip_bf16.h>

#define N_NODES 100000
#define N_EDGES 800000
#define EPS 1e-5f
#define NBANK 32
#define HB_BLOCKS 256
#define HB_PER 3125          // 256 * 3125 = 800000 exactly
#define CS_GPB 64            // cscatter blocks per coarse bucket
#define BUCKET_N 12500       // 8 * 12500 = 100000 exactly
#define MROW 68              // LDS mean row stride in dwords (64 + 4 pad)

typedef __attribute__((ext_vector_type(8))) short short8;
typedef __attribute__((ext_vector_type(4))) float floatx4;

__device__ __forceinline__ unsigned short f2b(float f) {
    unsigned int u = __float_as_uint(f);
    u = (u + 0x7fffu + ((u >> 16) & 1u)) >> 16;   // round-to-nearest-even
    return (unsigned short)u;
}
__device__ __forceinline__ float blo(unsigned int u) { return __uint_as_float(u << 16); }
__device__ __forceinline__ float bhi(unsigned int u) { return __uint_as_float(u & 0xffff0000u); }
__device__ __forceinline__ float b2f(unsigned short s) {
    return __uint_as_float(((unsigned int)s) << 16);
}

// ---------------- fused: cvt x->bf16 (blocks 0..12499) + dst hist (12500..) --
__global__ void __launch_bounds__(256) prep_k(const float* __restrict__ x,
                                              unsigned short* __restrict__ o,
                                              const int* __restrict__ dst,
                                              unsigned int* __restrict__ cnt,
                                              unsigned int* __restrict__ bhist) {
    if (blockIdx.x < 12500) {
        int i = blockIdx.x * 256 + threadIdx.x;   // 12500*256 = N_NODES*32 exactly
        float4 v = ((const float4*)x)[i];
        ushort4 r;
        r.x = f2b(v.x); r.y = f2b(v.y); r.z = f2b(v.z); r.w = f2b(v.w);
        ((ushort4*)o)[i] = r;
        return;
    }
    __shared__ unsigned int lh[8];
    int hb = blockIdx.x - 12500;
    if (threadIdx.x < 8) lh[threadIdx.x] = 0;
    __syncthreads();
    int start = hb * HB_PER;
    for (int i = threadIdx.x; i < HB_PER; i += 256) {
        int d = dst[start + i];
        atomicAdd(&cnt[d], 1u);
        atomicAdd(&lh[(unsigned int)d / BUCKET_N], 1u);
    }
    __syncthreads();
    if (threadIdx.x < 8) bhist[threadIdx.x * HB_BLOCKS + hb] = lh[threadIdx.x];
}

// ---------------- pack [Wl;Wr] (K=256 x Hreal) into MFMA B-fragment order ----
__device__ __forceinline__ void pack_one(const float* __restrict__ Wl,
                                         const float* __restrict__ Wr,
                                         unsigned short* __restrict__ out,
                                         int Hreal, int NCT, int tid) {
    int i = tid & 7;
    int lane = (tid >> 3) & 63;
    int q = tid >> 9;
    int c = q % NCT;
    int t = q / NCT;
    int k = t * 32 + (lane >> 4) * 8 + i;
    int n = c * 16 + (lane & 15);
    float v = 0.f;
    if (n < Hreal) v = (k < 128) ? Wl[k * Hreal + n] : Wr[(k - 128) * Hreal + n];
    out[tid] = f2b(v);
}

__global__ void __launch_bounds__(256) pack_all(const float* __restrict__ Wl0, const float* __restrict__ Wr0,
                                                const float* __restrict__ Wl1, const float* __restrict__ Wr1,
                                                const float* __restrict__ Wl2, const float* __restrict__ Wr2,
                                                unsigned short* __restrict__ W0p,
                                                unsigned short* __restrict__ W1p,
                                                unsigned short* __restrict__ W2p) {
    int tid = blockIdx.x * 256 + threadIdx.x;
    if (tid < 32768) pack_one(Wl0, Wr0, W0p, 128, 8, tid);
    else if (tid < 65536) pack_one(Wl1, Wr1, W1p, 128, 8, tid - 32768);
    else if (tid < 77824) pack_one(Wl2, Wr2, W2p, 40, 3, tid - 65536);
}

// ---------------- CSR scans -------------------------------------------------
__global__ void scan1(const unsigned int* __restrict__ cnt, unsigned int* __restrict__ rowptr,
                      unsigned int* __restrict__ bsum) {
    __shared__ unsigned int sh[256];
    int t = threadIdx.x;
    int i = blockIdx.x * 256 + t;
    unsigned int v = (i < N_NODES) ? cnt[i] : 0u;
    sh[t] = v; __syncthreads();
    for (int off = 1; off < 256; off <<= 1) {
        unsigned int add = (t >= off) ? sh[t - off] : 0u;
        __syncthreads();
        sh[t] += add;
        __syncthreads();
    }
    if (i < N_NODES) rowptr[i] = sh[t] - v;  // exclusive within block
    if (t == 255) bsum[blockIdx.x] = sh[255];
}

// fused: block 0 = scan2 (512 threads over 391 bsums); block 1 = bscan (bhist)
__global__ void scan2_bscan(const unsigned int* __restrict__ bsum, unsigned int* __restrict__ boff,
                            int nb, unsigned int* __restrict__ A) {
    if (blockIdx.x == 0) {
        __shared__ unsigned int sh[512];
        int t = threadIdx.x;
        unsigned int v = (t < nb) ? bsum[t] : 0u;
        sh[t] = v; __syncthreads();
        for (int off = 1; off < 512; off <<= 1) {
            unsigned int add = (t >= off) ? sh[t - off] : 0u;
            __syncthreads();
            sh[t] += add;
            __syncthreads();
        }
        if (t < nb) boff[t] = sh[t] - v;
        return;
    }
    // bscan over A[8*HB_BLOCKS]; threads >=256 only participate in barriers
    __shared__ unsigned int part[256];
    int t = threadIdx.x;
    unsigned int v[8];
    unsigned int s = 0;
    if (t < 256) {
#pragma unroll
        for (int i = 0; i < 8; i++) { v[i] = A[t * 8 + i]; s += v[i]; }
        part[t] = s;
    }
    __syncthreads();
    for (int off = 1; off < 256; off <<= 1) {
        unsigned int add = (t < 256 && t >= off) ? part[t - off] : 0u;
        __syncthreads();
        if (t < 256) part[t] += add;
        __syncthreads();
    }
    if (t < 256) {
        unsigned int base = part[t] - s;  // exclusive
#pragma unroll
        for (int i = 0; i < 8; i++) { unsigned int old = v[i]; A[t * 8 + i] = base; base += old; }
    }
}

// fused: blocks 0..390 = scan3 (rowptr finalize); blocks 391..646 = bscatter
__global__ void __launch_bounds__(256) scan3_bscatter(unsigned int* __restrict__ rowptr,
                                                      const unsigned int* __restrict__ boff,
                                                      unsigned int* __restrict__ cursor,
                                                      const int* __restrict__ src,
                                                      const int* __restrict__ dst,
                                                      const unsigned int* __restrict__ boffs,
                                                      unsigned int* __restrict__ ebuf) {
    if (blockIdx.x < 391) {
        int i = blockIdx.x * 256 + threadIdx.x;
        if (i < N_NODES) {
            unsigned int r = rowptr[i] + boff[blockIdx.x];
            rowptr[i] = r;
            cursor[i] = r;
        }
        if (i == N_NODES) rowptr[N_NODES] = N_EDGES;
        return;
    }
    __shared__ unsigned int cur[8];
    int bb = blockIdx.x - 391;
    if (threadIdx.x < 8) cur[threadIdx.x] = boffs[threadIdx.x * HB_BLOCKS + bb];
    __syncthreads();
    int start = bb * HB_PER;
    for (int i = threadIdx.x; i < HB_PER; i += 256) {
        int d = dst[start + i];
        int s = src[start + i];
        unsigned int b = (unsigned int)d / BUCKET_N;
        unsigned int dl = (unsigned int)d - b * BUCKET_N;
        unsigned int pos = atomicAdd(&cur[b], 1u);
        ebuf[pos] = (unsigned int)s | (dl << 17);
    }
}

__global__ void __launch_bounds__(256) cscatter(const unsigned int* __restrict__ ebuf,
                                                const unsigned int* __restrict__ rowptr,
                                                unsigned int* __restrict__ cursor,
                                                int* __restrict__ srclist) {
    int g = blockIdx.x & 7;
    int gblk = blockIdx.x >> 3;
    unsigned int estart = rowptr[g * BUCKET_N];
    unsigned int eend = (g == 7) ? N_EDGES : rowptr[(g + 1) * BUCKET_N];
    unsigned int nume = eend - estart;
    unsigned int per = (nume + CS_GPB - 1) / CS_GPB;
    unsigned int s0 = estart + gblk * per;
    unsigned int s1 = s0 + per; if (s1 > eend) s1 = eend;
    unsigned int nodebase = g * BUCKET_N;
    for (unsigned int i = s0 + threadIdx.x; i < s1; i += 256) {
        unsigned int p = ebuf[i];
        unsigned int s = p & 0x1FFFFu;
        unsigned int node = nodebase + (p >> 17);
        unsigned int pos = atomicAdd(&cursor[node], 1u);
        srclist[pos] = (int)s;
    }
}

// ---------------- phase-1: aggregate 16 nodes, 1 node/group ------------------
// R14: R13 structure + srclist software pipeline (next batch's indices issue
// before current batch's accumulate -- indices depend only on p, so the gather
// chain drops the per-iteration srclist round trip; traffic-neutral, unlike
// R12's unroll-8 which thrashed L2).
template<int BN>
__device__ __forceinline__ void agg_phase16(const unsigned short* __restrict__ hb,
                                            const unsigned int* __restrict__ rowptr,
                                            const int* __restrict__ srclist,
                                            unsigned int* __restrict__ smean,
                                            const float* __restrict__ sc,
                                            const float* __restrict__ sh,
                                            int wave, int g, int l, int blockrow) {
    const uint4* hp = (const uint4*)hb;
    int nl = wave * 4 + g;
    int node = blockrow + nl;   // grid is N/16 exactly -> always < N_NODES
    float f0 = 0.f, f1 = 0.f, f2 = 0.f, f3 = 0.f, f4 = 0.f, f5 = 0.f, f6 = 0.f, f7 = 0.f;
    float sc0r = 0.f, sc1r = 0.f, sc2r = 0.f, sc3r = 0.f, sc4r = 0.f, sc5r = 0.f, sc6r = 0.f, sc7r = 0.f;
    float sh0r = 0.f, sh1r = 0.f, sh2r = 0.f, sh3r = 0.f, sh4r = 0.f, sh5r = 0.f, sh6r = 0.f, sh7r = 0.f;
    if (BN) {
        const float* s0 = sc + l * 8;
        const float* s1 = sh + l * 8;
        sc0r = s0[0]; sc1r = s0[1]; sc2r = s0[2]; sc3r = s0[3];
        sc4r = s0[4]; sc5r = s0[5]; sc6r = s0[6]; sc7r = s0[7];
        sh0r = s1[0]; sh1r = s1[1]; sh2r = s1[2]; sh3r = s1[3];
        sh4r = s1[4]; sh5r = s1[5]; sh6r = s1[6]; sh7r = s1[7];
    }
    unsigned int b = rowptr[node], e = rowptr[node + 1];
    unsigned int p = b;
#define ACC8(U) { \
    if (BN) { \
        f0 += fmaxf(0.f, fmaf(blo(U.x), sc0r, sh0r)); \
        f1 += fmaxf(0.f, fmaf(bhi(U.x), sc1r, sh1r)); \
        f2 += fmaxf(0.f, fmaf(blo(U.y), sc2r, sh2r)); \
        f3 += fmaxf(0.f, fmaf(bhi(U.y), sc3r, sh3r)); \
        f4 += fmaxf(0.f, fmaf(blo(U.z), sc4r, sh4r)); \
        f5 += fmaxf(0.f, fmaf(bhi(U.z), sc5r, sh5r)); \
        f6 += fmaxf(0.f, fmaf(blo(U.w), sc6r, sh6r)); \
        f7 += fmaxf(0.f, fmaf(bhi(U.w), sc7r, sh7r)); \
    } else { \
        f0 += blo(U.x); f1 += bhi(U.x); f2 += blo(U.y); f3 += bhi(U.y); \
        f4 += blo(U.z); f5 += bhi(U.z); f6 += blo(U.w); f7 += bhi(U.w); \
    } }
    int s0 = 0, s1 = 0, s2 = 0, s3 = 0;
    bool have = (p + 4 <= e);
    if (have) { s0 = srclist[p]; s1 = srclist[p + 1]; s2 = srclist[p + 2]; s3 = srclist[p + 3]; }
    while (have) {
        uint4 u0 = hp[(size_t)s0 * 16 + l];
        uint4 u1 = hp[(size_t)s1 * 16 + l];
        uint4 u2 = hp[(size_t)s2 * 16 + l];
        uint4 u3 = hp[(size_t)s3 * 16 + l];
        p += 4;
        have = (p + 4 <= e);
        if (have) { s0 = srclist[p]; s1 = srclist[p + 1]; s2 = srclist[p + 2]; s3 = srclist[p + 3]; }
        ACC8(u0); ACC8(u1); ACC8(u2); ACC8(u3);
    }
    if (p + 2 <= e) {
        int t0 = srclist[p];
        int t1 = srclist[p + 1];
        uint4 u0 = hp[(size_t)t0 * 16 + l];
        uint4 u1 = hp[(size_t)t1 * 16 + l];
        ACC8(u0); ACC8(u1);
        p += 2;
    }
    if (p < e) {
        int t0 = srclist[p];
        uint4 u0 = hp[(size_t)t0 * 16 + l];
        ACC8(u0);
    }
#undef ACC8
    unsigned int deg = e - b;
    float r = 1.0f / (float)(deg > 1u ? deg : 1u);
    uint4 o;
    o.x = (unsigned int)f2b(f0 * r) | ((unsigned int)f2b(f1 * r) << 16);
    o.y = (unsigned int)f2b(f2 * r) | ((unsigned int)f2b(f3 * r) << 16);
    o.z = (unsigned int)f2b(f4 * r) | ((unsigned int)f2b(f5 * r) << 16);
    o.w = (unsigned int)f2b(f6 * r) | ((unsigned int)f2b(f7 * r) << 16);
    *(uint4*)&smean[nl * MROW + l * 4] = o;
}

// bn+relu+repack an 8-element bf16 fragment using LDS-staged sc/sh (root rows)
__device__ __forceinline__ short8 bn_pack8(short8 raw, const float* __restrict__ scb,
                                           const float* __restrict__ shb, int koff) {
    short8 r;
#pragma unroll
    for (int i = 0; i < 8; i++) {
        float v = b2f((unsigned short)raw[i]);
        v = fmaxf(0.f, fmaf(v, scb[koff + i], shb[koff + i]));
        r[i] = (short)f2b(v);
    }
    return r;
}

// ---------------- fused agg + GEMM L0/L1 + BN stats + bf16 C -----------------
// 16-row blocks, grid 6250 (= N/16). Phase 2: wave w handles cols [32w,32w+32)
// of all 16 rows (acc = 8 VGPRs). BN=1: input is pre-BN C of previous layer;
// relu(bn()) applied inline in gather and root-row loads.
template<int BN>
__global__ void __launch_bounds__(256) gemm2f_k(const unsigned short* __restrict__ hb,
                                                const unsigned int* __restrict__ rowptr,
                                                const int* __restrict__ srclist,
                                                const float* __restrict__ sc,
                                                const float* __restrict__ sh,
                                                const unsigned short* __restrict__ Bp,
                                                unsigned short* __restrict__ outb,
                                                float* __restrict__ sums) {
    __shared__ unsigned int smean[16 * MROW];
    __shared__ float lds_s[128];
    __shared__ float lds_s2[128];
    __shared__ float scb[128];
    __shared__ float shb[128];
    int wave = threadIdx.x >> 6;
    int lane = threadIdx.x & 63;
    int quad = lane >> 4;
    int l15 = lane & 15;
    int blockrow = blockIdx.x * 16;

    if (threadIdx.x < 128) {
        lds_s[threadIdx.x] = 0.f; lds_s2[threadIdx.x] = 0.f;
        if (BN) { scb[threadIdx.x] = sc[threadIdx.x]; shb[threadIdx.x] = sh[threadIdx.x]; }
    }
    if (BN) __syncthreads();   // scb/shb visible to phase 2 root loads

    agg_phase16<BN>(hb, rowptr, srclist, smean, sc, sh, wave, quad, l15, blockrow);
    __syncthreads();

    floatx4 acc[2];
    acc[0] = (floatx4){0.f, 0.f, 0.f, 0.f};
    acc[1] = (floatx4){0.f, 0.f, 0.f, 0.f};

    int r0 = blockrow + l15;   // always < N_NODES (exact division)

#pragma unroll
    for (int t = 0; t < 8; t++) {
        short8 a0;
        if (t < 4) {
            a0 = *(const short8*)&smean[l15 * MROW + t * 16 + quad * 4];
        } else {
            int koff = (t & 3) * 32 + quad * 8;
            short8 raw = *(const short8*)(hb + (size_t)r0 * 128 + koff);
            a0 = BN ? bn_pack8(raw, scb, shb, koff) : raw;
        }
#pragma unroll
        for (int c = 0; c < 2; c++) {
            int cidx = wave * 2 + c;
            short8 bf = *(const short8*)(Bp + ((size_t)(t * 8 + cidx) * 64 + lane) * 8);
            acc[c] = __builtin_amdgcn_mfma_f32_16x16x32_bf16(a0, bf, acc[c], 0, 0, 0);
        }
    }

#pragma unroll
    for (int c = 0; c < 2; c++) {
        int col = wave * 32 + c * 16 + l15;
        float s = 0.f, s2 = 0.f;
#pragma unroll
        for (int r = 0; r < 4; r++) {
            int row = blockrow + quad * 4 + r;
            float v = acc[c][r];
            outb[(size_t)row * 128 + col] = f2b(v);
            s += v; s2 += v * v;
        }
        s += __shfl_xor(s, 16);  s += __shfl_xor(s, 32);
        s2 += __shfl_xor(s2, 16); s2 += __shfl_xor(s2, 32);
        if (quad == 0) {
            atomicAdd(&lds_s[col], s);
            atomicAdd(&lds_s2[col], s2);
        }
    }

    __syncthreads();
    if (threadIdx.x < 128) {
        int bank = blockIdx.x & (NBANK - 1);
        atomicAdd(&sums[bank * 256 + threadIdx.x], lds_s[threadIdx.x]);
        atomicAdd(&sums[bank * 256 + 128 + threadIdx.x], lds_s2[threadIdx.x]);
    }
}

// ---------------- layer-2 dense: P = h2@Wl2 (bf16, 40 cols), Q = h2@Wr2+b2 ---
// 192 threads (3 waves), each wave owns one 16-col tile of [0,48); cols >=40
// discarded. h2 = relu(bn1(C1)) applied inline.
__global__ void __launch_bounds__(192) dense_k(const unsigned short* __restrict__ hb,
                                               const float* __restrict__ sc,
                                               const float* __restrict__ sh,
                                               const unsigned short* __restrict__ Bp,
                                               const float* __restrict__ bias,
                                               unsigned short* __restrict__ P,
                                               float* __restrict__ Q) {
    __shared__ float scb[128];
    __shared__ float shb[128];
    int wave = threadIdx.x >> 6;
    int lane = threadIdx.x & 63;
    int quad = lane >> 4;
    int l15 = lane & 15;
    int blockrow = blockIdx.x * 16;

    if (threadIdx.x < 128) { scb[threadIdx.x] = sc[threadIdx.x]; shb[threadIdx.x] = sh[threadIdx.x]; }
    __syncthreads();

    int r0 = blockrow + l15;
    short8 af[4];
#pragma unroll
    for (int t = 0; t < 4; t++) {
        int koff = t * 32 + quad * 8;
        short8 raw = *(const short8*)(hb + (size_t)r0 * 128 + koff);
        af[t] = bn_pack8(raw, scb, shb, koff);
    }

    floatx4 aP = (floatx4){0.f, 0.f, 0.f, 0.f};
    floatx4 aQ = (floatx4){0.f, 0.f, 0.f, 0.f};
#pragma unroll
    for (int t = 0; t < 4; t++) {
        short8 bl = *(const short8*)(Bp + ((size_t)(t * 3 + wave) * 64 + lane) * 8);
        aP = __builtin_amdgcn_mfma_f32_16x16x32_bf16(af[t], bl, aP, 0, 0, 0);
    }
#pragma unroll
    for (int t = 0; t < 4; t++) {
        short8 br = *(const short8*)(Bp + ((size_t)((t + 4) * 3 + wave) * 64 + lane) * 8);
        aQ = __builtin_amdgcn_mfma_f32_16x16x32_bf16(af[t], br, aQ, 0, 0, 0);
    }
    int col = wave * 16 + l15;
    if (col < 40) {
#pragma unroll
        for (int r = 0; r < 4; r++) {
            int row = blockrow + quad * 4 + r;
            P[(size_t)row * 40 + col] = f2b(aP[r]);
            Q[(size_t)row * 40 + col] = aQ[r] + bias[col];
        }
    }
}

// ---------------- layer-2 aggregate: out = mean(P[src]) + Q ------------------
// 8-lane groups, 32 nodes/block, grid 3125 (= N/32). 80B rows: lanes 0-4 carry
// real cols; lanes 5-7 alias lane-0's line (same cacheline -> no extra traffic,
// no divergence) and are masked at the write.
__global__ void __launch_bounds__(256) agg40_k(const unsigned short* __restrict__ P,
                                               const unsigned int* __restrict__ rowptr,
                                               const int* __restrict__ srclist,
                                               const float* __restrict__ Q,
                                               float* __restrict__ out) {
    int tid = threadIdx.x;
    int g = tid >> 3;        // group 0..31
    int l = tid & 7;         // lane in group
    int ll = l < 5 ? l : 0;  // lanes 5-7 alias lane 0 (no extra lines)
    int node = blockIdx.x * 32 + g;   // 3125*32 = 100000 exactly
    const uint4* pp = (const uint4*)P;
    float f0 = 0.f, f1 = 0.f, f2 = 0.f, f3 = 0.f, f4 = 0.f, f5 = 0.f, f6 = 0.f, f7 = 0.f;
    unsigned int b = rowptr[node], e = rowptr[node + 1];
    unsigned int p = b;
#define ACC8(U) { f0 += blo(U.x); f1 += bhi(U.x); f2 += blo(U.y); f3 += bhi(U.y); \
                  f4 += blo(U.z); f5 += bhi(U.z); f6 += blo(U.w); f7 += bhi(U.w); }
    int s0 = 0, s1 = 0, s2 = 0, s3 = 0;
    bool have = (p + 4 <= e);
    if (have) { s0 = srclist[p]; s1 = srclist[p + 1]; s2 = srclist[p + 2]; s3 = srclist[p + 3]; }
    while (have) {
        uint4 u0 = pp[(size_t)s0 * 5 + ll];
        uint4 u1 = pp[(size_t)s1 * 5 + ll];
        uint4 u2 = pp[(size_t)s2 * 5 + ll];
        uint4 u3 = pp[(size_t)s3 * 5 + ll];
        p += 4;
        have = (p + 4 <= e);
        if (have) { s0 = srclist[p]; s1 = srclist[p + 1]; s2 = srclist[p + 2]; s3 = srclist[p + 3]; }
        ACC8(u0); ACC8(u1); ACC8(u2); ACC8(u3);
    }
    if (p + 2 <= e) {
        int t0 = srclist[p];
        int t1 = srclist[p + 1];
        uint4 u0 = pp[(size_t)t0 * 5 + ll];
        uint4 u1 = pp[(size_t)t1 * 5 + ll];
        ACC8(u0); ACC8(u1);
        p += 2;
    }
    if (p < e) {
        int t0 = srclist[p];
        uint4 u0 = pp[(size_t)t0 * 5 + ll];
        ACC8(u0);
    }
#undef ACC8
    unsigned int deg = e - b;
    float r = 1.0f / (float)(deg > 1u ? deg : 1u);
    if (l < 5) {   // cols l*8 .. l*8+8 of 40
        size_t base = (size_t)node * 40 + l * 8;
        float4 o1, o2;
        o1.x = f0 * r + Q[base + 0]; o1.y = f1 * r + Q[base + 1];
        o1.z = f2 * r + Q[base + 2]; o1.w = f3 * r + Q[base + 3];
        o2.x = f4 * r + Q[base + 4]; o2.y = f5 * r + Q[base + 5];
        o2.z = f6 * r + Q[base + 6]; o2.w = f7 * r + Q[base + 7];
        *(float4*)(out + base) = o1;
        *(float4*)(out + base + 4) = o2;
    }
}

// ---------------- BN finalize (reduce 32 banks) ------------------------------
__global__ void bn_finalize(const float* __restrict__ sums, const float* __restrict__ g,
                            const float* __restrict__ be, float* __restrict__ sc,
                            float* __restrict__ sh) {
    __shared__ float lds[256];
    int t = threadIdx.x;
    float s = 0.f;
#pragma unroll 8
    for (int bk = 0; bk < NBANK; bk++) s += sums[bk * 256 + t];
    lds[t] = s;
    __syncthreads();
    if (t < 128) {
        float inv_n = 1.0f / (float)N_NODES;
        float mu = lds[t] * inv_n;
        float var = lds[128 + t] * inv_n - mu * mu;
        float sf = g[t] * rsqrtf(var + EPS);
        sc[t] = sf;
        sh[t] = be[t] - mu * sf;
    }
}

// ---------------- host ----------------
extern "C" void kernel_launch(void* const* d_in, const int* in_sizes, int n_in,
                              void* d_out, int out_size, void* d_ws, size_t ws_size,
                              hipStream_t stream) {
    const float* x   = (const float*)d_in[0];
    const int* ei    = (const int*)d_in[1];     // [2, E] int32: row 0 = src, row 1 = dst
    const float* Wl0 = (const float*)d_in[2];
    const float* Wr0 = (const float*)d_in[3];
    const float* Wl1 = (const float*)d_in[4];
    const float* Wr1 = (const float*)d_in[5];
    const float* Wl2 = (const float*)d_in[6];
    const float* Wr2 = (const float*)d_in[7];
    const float* b2  = (const float*)d_in[8];
    const float* g0  = (const float*)d_in[9];
    const float* be0 = (const float*)d_in[10];
    const float* g1  = (const float*)d_in[11];
    const float* be1 = (const float*)d_in[12];

    char* ws = (char*)d_ws;
    size_t off = 0;
    auto alloc = [&](size_t bytes) -> void* {
        void* p = ws + off;
        off += (bytes + 4095) & ~(size_t)4095;
        return p;
    };

    const size_t NB16 = (size_t)N_NODES * 128 * 2;  // 25.6 MB bf16 feature buffer
    unsigned short* xb   = (unsigned short*)alloc(NB16);   // x bf16; reused as Q (fp32 16MB)
    unsigned short* C0b  = (unsigned short*)alloc(NB16);   // layer-0 pre-BN C; reused as P40
    unsigned short* C1b  = (unsigned short*)alloc(NB16);   // layer-1 pre-BN C
    // cnt + sums0 + sums1 allocated contiguously -> ONE memset covers all three
    unsigned int* cnt    = (unsigned int*)alloc((size_t)N_NODES * 4);
    float* sums0         = (float*)alloc(NBANK * 256 * 4);
    float* sums1         = (float*)alloc(NBANK * 256 * 4);
    unsigned int* rowptr = (unsigned int*)alloc((size_t)(N_NODES + 1) * 4);
    unsigned int* cursor = (unsigned int*)alloc((size_t)N_NODES * 4);
    int* srclist         = (int*)alloc((size_t)N_EDGES * 4);
    unsigned int* ebuf   = (unsigned int*)alloc((size_t)N_EDGES * 4);
    unsigned int* bhist  = (unsigned int*)alloc(8 * HB_BLOCKS * 4);
    unsigned int* bsum   = (unsigned int*)alloc(512 * 4);
    unsigned int* boff   = (unsigned int*)alloc(512 * 4);
    float* sc            = (float*)alloc(128 * 4);
    float* sh            = (float*)alloc(128 * 4);
    unsigned short* W0p  = (unsigned short*)alloc(8 * 8 * 64 * 8 * 2);
    unsigned short* W1p  = (unsigned short*)alloc(8 * 8 * 64 * 8 * 2);
    unsigned short* W2p  = (unsigned short*)alloc(3 * 8 * 64 * 8 * 2);

    unsigned short* P40  = C0b;           // 8 MB, C0 dead after layer-1 gemm
    float* Q             = (float*)xb;    // 16 MB, xb dead after layer-0 gemm

    const int* srcp = ei;
    const int* dstp = ei + N_EDGES;

    // single memset over cnt|sums0|sums1 (contiguous, 4K-rounded slabs)
    size_t cnt_slab  = ((size_t)N_NODES * 4 + 4095) & ~(size_t)4095;
    size_t sums_slab = ((size_t)NBANK * 256 * 4 + 4095) & ~(size_t)4095;
    hipMemsetAsync(cnt, 0, cnt_slab + 2 * sums_slab, stream);

    // fused cvt + hist; fused weight packs
    prep_k<<<12756, 256, 0, stream>>>(x, xb, dstp, cnt, bhist);
    pack_all<<<304, 256, 0, stream>>>(Wl0, Wr0, Wl1, Wr1, Wl2, Wr2, W0p, W1p, W2p);

    // CSR scan chain (fused where independent)
    scan1<<<391, 256, 0, stream>>>(cnt, rowptr, bsum);
    scan2_bscan<<<2, 512, 0, stream>>>(bsum, boff, 391, bhist);
    scan3_bscatter<<<647, 256, 0, stream>>>(rowptr, boff, cursor, srcp, dstp, bhist, ebuf);
    cscatter<<<8 * CS_GPB, 256, 0, stream>>>(ebuf, rowptr, cursor, srclist);

    // layer 0: agg+gemm from x (no input BN) -> C0, stats0
    gemm2f_k<0><<<6250, 256, 0, stream>>>(xb, rowptr, srclist, nullptr, nullptr, W0p, C0b, sums0);
    bn_finalize<<<1, 256, 0, stream>>>(sums0, g0, be0, sc, sh);

    // layer 1: agg+gemm from C0 with inline relu(bn0) -> C1, stats1
    gemm2f_k<1><<<6250, 256, 0, stream>>>(C0b, rowptr, srclist, sc, sh, W1p, C1b, sums1);
    bn_finalize<<<1, 256, 0, stream>>>(sums1, g1, be1, sc, sh);

    // layer 2: transform-first (mean is linear)
    dense_k<<<6250, 192, 0, stream>>>(C1b, sc, sh, W2p, b2, P40, Q);
    agg40_k<<<3125, 256, 0, stream>>>(P40, rowptr, srclist, Q, (float*)d_out);

    (void)in_sizes; (void)n_in; (void)out_size; (void)ws_size;
}